// Round 1
// baseline (904.659 us; speedup 1.0000x reference)
//
#include <hip/hip_runtime.h>

typedef unsigned int uint;
typedef unsigned short u16;

typedef __attribute__((ext_vector_type(8))) short short8;
typedef __attribute__((ext_vector_type(8))) u16 u16x8;
typedef __attribute__((ext_vector_type(4))) float f32x4;

#define NN 50000
#define EE 1600000
#define ETOT (EE + NN)
#define DIN 768
#define DD 256

__device__ __forceinline__ u16 f2bf(float f) {
  uint u = __builtin_bit_cast(uint, f);
  uint r = u + 0x7fffu + ((u >> 16) & 1u);
  return (u16)(r >> 16);
}

__device__ __forceinline__ float dot4(float4 a, float4 b) {
  return a.x * b.x + a.y * b.y + a.z * b.z + a.w * b.w;
}

__device__ __forceinline__ float wred_sum(float v) {
#pragma unroll
  for (int off = 32; off > 0; off >>= 1) v += __shfl_xor(v, off);
  return v;
}

// ---------------- W transpose + bf16 convert: W[K][N] -> Wt[N][K] ----------------
__global__ void wt_kernel(const float* __restrict__ W, u16* __restrict__ Wt, int K, int N) {
  int i = blockIdx.x * 256 + threadIdx.x;
  if (i >= K * N) return;
  int k = i / N, n = i % N;
  Wt[(size_t)n * K + k] = f2bf(W[i]);
}

// ---------------- GEMM: C[M][256] = A[M][K] (fp32) @ Bt[256][K] (bf16)^T ----------------
#define BM 128
#define BN 128
#define BK 64

__global__ __launch_bounds__(256) void gemm_bt(const float* __restrict__ A,
                                               const u16* __restrict__ Bt,
                                               float* __restrict__ C, int M, int K) {
  __shared__ u16 As[BM * BK];
  __shared__ u16 Bs[BN * BK];
  const int m0 = blockIdx.x * BM;
  const int n0 = blockIdx.y * BN;
  const int tid = threadIdx.x;
  const int lane = tid & 63;
  const int wv = tid >> 6;
  const int wm = wv >> 1, wn = wv & 1;

  f32x4 acc[4][4] = {};

  const int sr = tid >> 1;         // staging row 0..127
  const int skc = (tid & 1) * 32;  // k sub-offset

  for (int k0 = 0; k0 < K; k0 += BK) {
    // stage A (fp32 -> bf16, swizzled)
    {
      int grow = m0 + sr;
      float4 f[8];
      if (grow < M) {
        const float4* src = reinterpret_cast<const float4*>(A + (size_t)grow * K + k0 + skc);
#pragma unroll
        for (int i = 0; i < 8; ++i) f[i] = src[i];
      } else {
#pragma unroll
        for (int i = 0; i < 8; ++i) f[i] = make_float4(0.f, 0.f, 0.f, 0.f);
      }
#pragma unroll
      for (int i = 0; i < 4; ++i) {
        u16x8 v;
        v[0] = f2bf(f[2 * i].x); v[1] = f2bf(f[2 * i].y);
        v[2] = f2bf(f[2 * i].z); v[3] = f2bf(f[2 * i].w);
        v[4] = f2bf(f[2 * i + 1].x); v[5] = f2bf(f[2 * i + 1].y);
        v[6] = f2bf(f[2 * i + 1].z); v[7] = f2bf(f[2 * i + 1].w);
        int k = skc + i * 8;
        int idx = (sr << 6) + (k ^ ((sr & 7) << 3));
        *reinterpret_cast<u16x8*>(&As[idx]) = v;
      }
    }
    // stage B (already bf16, swizzled copy)
    {
      const u16x8* src = reinterpret_cast<const u16x8*>(Bt + (size_t)(n0 + sr) * K + k0 + skc);
#pragma unroll
      for (int i = 0; i < 4; ++i) {
        u16x8 v = src[i];
        int k = skc + i * 8;
        int idx = (sr << 6) + (k ^ ((sr & 7) << 3));
        *reinterpret_cast<u16x8*>(&Bs[idx]) = v;
      }
    }
    __syncthreads();
#pragma unroll
    for (int kk = 0; kk < 2; ++kk) {
      short8 af[4], bfr[4];
      const int kb = kk * 32 + (lane >> 4) * 8;
#pragma unroll
      for (int m = 0; m < 4; ++m) {
        int r = wm * 64 + m * 16 + (lane & 15);
        int idx = (r << 6) + (kb ^ ((r & 7) << 3));
        af[m] = *reinterpret_cast<const short8*>(&As[idx]);
      }
#pragma unroll
      for (int n = 0; n < 4; ++n) {
        int c = wn * 64 + n * 16 + (lane & 15);
        int idx = (c << 6) + (kb ^ ((c & 7) << 3));
        bfr[n] = *reinterpret_cast<const short8*>(&Bs[idx]);
      }
#pragma unroll
      for (int m = 0; m < 4; ++m)
#pragma unroll
        for (int n = 0; n < 4; ++n)
          acc[m][n] = __builtin_amdgcn_mfma_f32_16x16x32_bf16(af[m], bfr[n], acc[m][n], 0, 0, 0);
    }
    __syncthreads();
  }
  // epilogue: C/D layout col=lane&15, row=(lane>>4)*4+reg
  const int rbase = m0 + wm * 64 + ((lane >> 4) << 2);
  const int cbase = n0 + wn * 64 + (lane & 15);
#pragma unroll
  for (int m = 0; m < 4; ++m) {
#pragma unroll
    for (int reg = 0; reg < 4; ++reg) {
      int row = rbase + m * 16 + reg;
      if (row < M) {
#pragma unroll
        for (int n = 0; n < 4; ++n) {
          C[(size_t)row * 256 + cbase + n * 16] = acc[m][n][reg];
        }
      }
    }
  }
}

// ---------------- per-node attention scalars: as[i]=h[i].a_src, ad[i]=h[i].a_dst ----------------
__global__ __launch_bounds__(256) void alphas_kernel(const float* __restrict__ h,
                                                     const float* __restrict__ a_src,
                                                     const float* __restrict__ a_dst,
                                                     float* __restrict__ as_, float* __restrict__ ad_,
                                                     int n) {
  int wid = (blockIdx.x * 256 + threadIdx.x) >> 6;
  int lane = threadIdx.x & 63;
  if (wid >= n) return;
  float4 hv = reinterpret_cast<const float4*>(h)[(size_t)wid * 64 + lane];
  float4 s4 = reinterpret_cast<const float4*>(a_src)[lane];
  float4 d4 = reinterpret_cast<const float4*>(a_dst)[lane];
  float ps = wred_sum(dot4(hv, s4));
  float pd = wred_sum(dot4(hv, d4));
  if (lane == 0) { as_[wid] = ps; ad_[wid] = pd; }
}

// ---------------- CSR build ----------------
__global__ void hist_kernel(const int* __restrict__ edge_dst, uint* __restrict__ cnt) {
  int i = blockIdx.x * 256 + threadIdx.x;
  if (i >= ETOT) return;
  int d = (i < EE) ? edge_dst[i] : (i - EE);
  atomicAdd(&cnt[d], 1u);
}

__global__ __launch_bounds__(1024) void scan_kernel(const uint* __restrict__ cnt,
                                                    uint* __restrict__ row_ptr,
                                                    uint* __restrict__ nxt, int n) {
  __shared__ uint wsum[16];
  __shared__ uint carry_sh;
  int tid = threadIdx.x, lane = tid & 63, w = tid >> 6;
  if (tid == 0) carry_sh = 0;
  __syncthreads();
  for (int base = 0; base < n; base += 1024) {
    int i = base + tid;
    uint v = (i < n) ? cnt[i] : 0u;
    uint x = v;
#pragma unroll
    for (int off = 1; off < 64; off <<= 1) {
      uint t = __shfl_up(x, off);
      if (lane >= off) x += t;
    }
    if (lane == 63) wsum[w] = x;
    __syncthreads();
    uint woff = 0;
    for (int k = 0; k < w; ++k) woff += wsum[k];
    uint carry = carry_sh;
    uint excl = carry + woff + x - v;
    if (i < n) { row_ptr[i] = excl; nxt[i] = excl; }
    __syncthreads();
    if (tid == 1023) carry_sh = carry + woff + x;
    __syncthreads();
  }
  if (threadIdx.x == 0) row_ptr[n] = carry_sh;
}

__global__ void scatter_kernel(const int* __restrict__ edge_src, const int* __restrict__ edge_dst,
                               uint* __restrict__ nxt, uint* __restrict__ csr_src) {
  int i = blockIdx.x * 256 + threadIdx.x;
  if (i >= ETOT) return;
  int s = (i < EE) ? edge_src[i] : (i - EE);
  int d = (i < EE) ? edge_dst[i] : (i - EE);
  uint pos = atomicAdd(&nxt[d], 1u);
  csr_src[pos] = (uint)s;
}

// ---------------- GAT aggregation: out[i] = relu( (sum_j w_ij h[j]) / (sum w + eps) + b ) ----------------
__global__ __launch_bounds__(256) void agg_kernel(const float* __restrict__ h,
                                                  const float* __restrict__ as_,
                                                  const float* __restrict__ ad_,
                                                  const uint* __restrict__ row_ptr,
                                                  const uint* __restrict__ csr_src,
                                                  const float* __restrict__ bias,
                                                  float* __restrict__ out, int n) {
  int wid = (blockIdx.x * 256 + threadIdx.x) >> 6;
  int lane = threadIdx.x & 63;
  if (wid >= n) return;
  uint start = row_ptr[wid], end = row_ptr[wid + 1];
  float adi = ad_[wid];
  const float4* __restrict__ h4 = reinterpret_cast<const float4*>(h);
  float ax = 0.f, ay = 0.f, az = 0.f, aw = 0.f;
  float denom = 0.f;
  for (uint base = start; base < end; base += 64) {
    int cnt = (int)(end - base);
    if (cnt > 64) cnt = 64;
    float w = 0.f;
    int s = 0;
    if (lane < cnt) {
      s = (int)csr_src[base + lane];
      float e = as_[s] + adi;
      e = e > 0.f ? e : 0.2f * e;
      w = __expf(e);
    }
    denom += w;
    for (int j = 0; j < cnt; ++j) {
      float wj = __shfl(w, j);
      int sj = __shfl(s, j);
      float4 hv = h4[(size_t)sj * 64 + lane];
      ax = fmaf(wj, hv.x, ax);
      ay = fmaf(wj, hv.y, ay);
      az = fmaf(wj, hv.z, az);
      aw = fmaf(wj, hv.w, aw);
    }
  }
  denom = wred_sum(denom);
  float inv = 1.f / (denom + 1e-16f);
  float4 b = reinterpret_cast<const float4*>(bias)[lane];
  float4 o;
  o.x = fmaxf(fmaf(ax, inv, b.x), 0.f);
  o.y = fmaxf(fmaf(ay, inv, b.y), 0.f);
  o.z = fmaxf(fmaf(az, inv, b.z), 0.f);
  o.w = fmaxf(fmaf(aw, inv, b.w), 0.f);
  reinterpret_cast<float4*>(out)[(size_t)wid * 64 + lane] = o;
}

// ---------------- Global attention pooling ----------------
__global__ __launch_bounds__(256) void pool1_kernel(const float* __restrict__ h,
                                                    const float* __restrict__ gate_w,
                                                    float* __restrict__ wexp,
                                                    float* __restrict__ partials, int n) {
  __shared__ float ps[4];
  int wid = (blockIdx.x * 256 + threadIdx.x) >> 6;
  int lane = threadIdx.x & 63;
  int w = threadIdx.x >> 6;
  float val = 0.f;
  if (wid < n) {
    float4 hv = reinterpret_cast<const float4*>(h)[(size_t)wid * 64 + lane];
    float4 g = reinterpret_cast<const float4*>(gate_w)[lane];
    float p = wred_sum(dot4(hv, g));
    val = __expf(p);
    if (lane == 0) wexp[wid] = val;
  }
  if (lane == 0) ps[w] = (wid < n) ? val : 0.f;
  __syncthreads();
  if (threadIdx.x == 0) partials[blockIdx.x] = ps[0] + ps[1] + ps[2] + ps[3];
}

__global__ __launch_bounds__(256) void pool2_kernel(const float* __restrict__ h,
                                                    const float* __restrict__ wexp,
                                                    float* __restrict__ pool_acc, int n) {
  __shared__ float red[4][256];
  int lane = threadIdx.x & 63, w = threadIdx.x >> 6;
  float ax = 0.f, ay = 0.f, az = 0.f, aw = 0.f;
  int stride = gridDim.x * 4;
  for (int i = blockIdx.x * 4 + w; i < n; i += stride) {
    float wv = wexp[i];
    float4 hv = reinterpret_cast<const float4*>(h)[(size_t)i * 64 + lane];
    ax = fmaf(wv, hv.x, ax);
    ay = fmaf(wv, hv.y, ay);
    az = fmaf(wv, hv.z, az);
    aw = fmaf(wv, hv.w, aw);
  }
  red[w][lane * 4 + 0] = ax;
  red[w][lane * 4 + 1] = ay;
  red[w][lane * 4 + 2] = az;
  red[w][lane * 4 + 3] = aw;
  __syncthreads();
  if (w == 0) {
#pragma unroll
    for (int c = 0; c < 4; ++c) {
      int f = lane * 4 + c;
      float t = red[0][f] + red[1][f] + red[2][f] + red[3][f];
      atomicAdd(&pool_acc[f], t);
    }
  }
}

__global__ __launch_bounds__(256) void pool3_kernel(const float* __restrict__ partials, int np,
                                                    const float* __restrict__ pool_acc,
                                                    float* __restrict__ out) {
  __shared__ float red[256];
  int tid = threadIdx.x;
  float s = 0.f;
  for (int i = tid; i < np; i += 256) s += partials[i];
  red[tid] = s;
  __syncthreads();
  for (int off = 128; off > 0; off >>= 1) {
    if (tid < off) red[tid] += red[tid + off];
    __syncthreads();
  }
  float denom = red[0];
  out[tid] = pool_acc[tid] / denom;
}

// ---------------- launch ----------------
extern "C" void kernel_launch(void* const* d_in, const int* in_sizes, int n_in,
                              void* d_out, int out_size, void* d_ws, size_t ws_size,
                              hipStream_t stream) {
  const float* x = (const float*)d_in[0];
  const int* edge = (const int*)d_in[1];
  const float* W0 = (const float*)d_in[2];
  const float* a_src0 = (const float*)d_in[3];
  const float* a_dst0 = (const float*)d_in[4];
  const float* b0 = (const float*)d_in[5];
  const float* W1 = (const float*)d_in[6];
  const float* a_src1 = (const float*)d_in[7];
  const float* a_dst1 = (const float*)d_in[8];
  const float* b1 = (const float*)d_in[9];
  const float* gate_w = (const float*)d_in[10];
  float* out = (float*)d_out;

  char* p = (char*)d_ws;
  size_t off = 0;
  auto take = [&](size_t bytes) -> char* {
    char* r = p + off;
    off = (off + bytes + 255) & ~(size_t)255;
    return r;
  };
  float* hA = (float*)take((size_t)NN * 256 * 4);
  float* hB = (float*)take((size_t)NN * 256 * 4);
  u16* Wt0 = (u16*)take((size_t)256 * 768 * 2);
  u16* Wt1 = (u16*)take((size_t)256 * 256 * 2);
  float* asb = (float*)take((size_t)NN * 4);
  float* adb = (float*)take((size_t)NN * 4);
  char* zero_base = p + off;
  uint* cnt = (uint*)take((size_t)NN * 4);
  float* pool_acc = (float*)take(256 * 4);
  size_t zero_bytes = (size_t)((p + off) - zero_base);
  uint* row_ptr = (uint*)take((size_t)(NN + 1) * 4);
  uint* nxt = (uint*)take((size_t)NN * 4);
  uint* csr = (uint*)take((size_t)ETOT * 4);
  float* wexp = (float*)take((size_t)NN * 4);
  float* partials = (float*)take((size_t)12500 * 4);

  const int* edge_src = edge;
  const int* edge_dst = edge + EE;

  hipMemsetAsync(zero_base, 0, zero_bytes, stream);

  wt_kernel<<<(768 * 256 + 255) / 256, 256, 0, stream>>>(W0, Wt0, 768, 256);
  wt_kernel<<<(256 * 256 + 255) / 256, 256, 0, stream>>>(W1, Wt1, 256, 256);

  hist_kernel<<<(ETOT + 255) / 256, 256, 0, stream>>>(edge_dst, cnt);
  scan_kernel<<<1, 1024, 0, stream>>>(cnt, row_ptr, nxt, NN);
  scatter_kernel<<<(ETOT + 255) / 256, 256, 0, stream>>>(edge_src, edge_dst, nxt, csr);

  dim3 ggrid((NN + BM - 1) / BM, 2);
  gemm_bt<<<ggrid, 256, 0, stream>>>(x, Wt0, hA, NN, 768);
  alphas_kernel<<<12500, 256, 0, stream>>>(hA, a_src0, a_dst0, asb, adb, NN);
  agg_kernel<<<12500, 256, 0, stream>>>(hA, asb, adb, row_ptr, csr, b0, hB, NN);

  gemm_bt<<<ggrid, 256, 0, stream>>>(hB, Wt1, hA, NN, 256);
  alphas_kernel<<<12500, 256, 0, stream>>>(hA, a_src1, a_dst1, asb, adb, NN);
  agg_kernel<<<12500, 256, 0, stream>>>(hA, asb, adb, row_ptr, csr, b1, hB, NN);

  pool1_kernel<<<12500, 256, 0, stream>>>(hB, gate_w, wexp, partials, NN);
  pool2_kernel<<<128, 256, 0, stream>>>(hB, wexp, pool_acc, NN);
  pool3_kernel<<<1, 256, 0, stream>>>(partials, 12500, pool_acc, out);
}

// Round 2
// 563.632 us; speedup vs baseline: 1.6051x; 1.6051x over previous
//
#include <hip/hip_runtime.h>

typedef unsigned int uint;
typedef unsigned short u16;

typedef __attribute__((ext_vector_type(8))) short short8;
typedef __attribute__((ext_vector_type(8))) u16 u16x8;
typedef __attribute__((ext_vector_type(4))) float f32x4;

#define NN 50000
#define EE 1600000
#define ETOT (EE + NN)

__device__ __forceinline__ u16 f2bf(float f) {
  uint u = __builtin_bit_cast(uint, f);
  uint r = u + 0x7fffu + ((u >> 16) & 1u);
  return (u16)(r >> 16);
}
__device__ __forceinline__ float bf2f(u16 h) {
  return __builtin_bit_cast(float, ((uint)h) << 16);
}
__device__ __forceinline__ float wred_sum(float v) {
#pragma unroll
  for (int off = 32; off > 0; off >>= 1) v += __shfl_xor(v, off);
  return v;
}

// ---------------- W transpose + bf16 convert: W[K][N] -> Wt[N][K] ----------------
__global__ void wt_kernel(const float* __restrict__ W, u16* __restrict__ Wt, int K, int N) {
  int i = blockIdx.x * 256 + threadIdx.x;
  if (i >= K * N) return;
  int k = i / N, n = i % N;
  Wt[(size_t)n * K + k] = f2bf(W[i]);
}

// ---------------- GEMM + fused alpha epilogue ----------------
// C[M][256] = A[M][K] @ Bt[256][K]^T ; writes bf16 C, and as_[r]=C[r].a_src,
// ad_[r]=C[r].a_dst via cross-lane reduce + atomicAdd (as_/ad_ pre-zeroed).
template <bool ABF16>
__global__ __launch_bounds__(512) void gemm_fused(const void* __restrict__ Avoid,
                                                  const u16* __restrict__ Bt,
                                                  u16* __restrict__ Cb,
                                                  const float* __restrict__ a_src,
                                                  const float* __restrict__ a_dst,
                                                  float* __restrict__ as_,
                                                  float* __restrict__ ad_,
                                                  int M, int K) {
  __shared__ __align__(16) u16 As[128 * 64];
  __shared__ __align__(16) u16 Bs[256 * 64];
  const int m0 = blockIdx.x * 128;
  const int tid = threadIdx.x;
  const int lane = tid & 63;
  const int wv = tid >> 6;
  const int wm = wv >> 2, wn = wv & 3;

  f32x4 acc[4][4] = {};

  const int sr = tid >> 2;          // A staging row 0..127
  const int skc = (tid & 3) * 16;   // A k sub-offset (16 elems)
  const int br = tid >> 1;          // B staging row 0..255
  const int bk = (tid & 1) * 32;    // B k sub-offset (32 elems)

  for (int k0 = 0; k0 < K; k0 += 64) {
    // stage A
    {
      int grow = m0 + sr;
      if constexpr (!ABF16) {
        const float* A = (const float*)Avoid;
        float4 f[4];
        if (grow < M) {
          const float4* src = reinterpret_cast<const float4*>(A + (size_t)grow * K + k0 + skc);
#pragma unroll
          for (int i = 0; i < 4; ++i) f[i] = src[i];
        } else {
#pragma unroll
          for (int i = 0; i < 4; ++i) f[i] = make_float4(0.f, 0.f, 0.f, 0.f);
        }
#pragma unroll
        for (int i = 0; i < 2; ++i) {
          u16x8 v;
          v[0] = f2bf(f[2 * i].x); v[1] = f2bf(f[2 * i].y);
          v[2] = f2bf(f[2 * i].z); v[3] = f2bf(f[2 * i].w);
          v[4] = f2bf(f[2 * i + 1].x); v[5] = f2bf(f[2 * i + 1].y);
          v[6] = f2bf(f[2 * i + 1].z); v[7] = f2bf(f[2 * i + 1].w);
          int k = skc + i * 8;
          int idx = (sr << 6) + (k ^ ((sr & 7) << 3));
          *reinterpret_cast<u16x8*>(&As[idx]) = v;
        }
      } else {
        const u16* A = (const u16*)Avoid;
        u16x8 v[2];
        if (grow < M) {
          const u16x8* src = reinterpret_cast<const u16x8*>(A + (size_t)grow * K + k0 + skc);
          v[0] = src[0]; v[1] = src[1];
        } else {
          v[0] = (u16x8)0; v[1] = (u16x8)0;
        }
#pragma unroll
        for (int i = 0; i < 2; ++i) {
          int k = skc + i * 8;
          int idx = (sr << 6) + (k ^ ((sr & 7) << 3));
          *reinterpret_cast<u16x8*>(&As[idx]) = v[i];
        }
      }
    }
    // stage B
    {
      const u16x8* src = reinterpret_cast<const u16x8*>(Bt + (size_t)br * K + k0 + bk);
#pragma unroll
      for (int i = 0; i < 4; ++i) {
        u16x8 v = src[i];
        int k = bk + i * 8;
        int idx = (br << 6) + (k ^ ((br & 7) << 3));
        *reinterpret_cast<u16x8*>(&Bs[idx]) = v;
      }
    }
    __syncthreads();
#pragma unroll
    for (int kk = 0; kk < 2; ++kk) {
      short8 af[4], bfr[4];
      const int kb = kk * 32 + (lane >> 4) * 8;
#pragma unroll
      for (int m = 0; m < 4; ++m) {
        int r = wm * 64 + m * 16 + (lane & 15);
        int idx = (r << 6) + (kb ^ ((r & 7) << 3));
        af[m] = *reinterpret_cast<const short8*>(&As[idx]);
      }
#pragma unroll
      for (int n = 0; n < 4; ++n) {
        int c = wn * 64 + n * 16 + (lane & 15);
        int idx = (c << 6) + (kb ^ ((c & 7) << 3));
        bfr[n] = *reinterpret_cast<const short8*>(&Bs[idx]);
      }
#pragma unroll
      for (int m = 0; m < 4; ++m)
#pragma unroll
        for (int n = 0; n < 4; ++n)
          acc[m][n] = __builtin_amdgcn_mfma_f32_16x16x32_bf16(af[m], bfr[n], acc[m][n], 0, 0, 0);
    }
    __syncthreads();
  }

  // epilogue: C/D layout col=lane&15 (within 16-frag), row=(lane>>4)*4+reg
  const int g = lane >> 4;
  const int cl = lane & 15;
  float asv[4], adv[4];
#pragma unroll
  for (int n = 0; n < 4; ++n) {
    int c = wn * 64 + n * 16 + cl;
    asv[n] = a_src[c];
    adv[n] = a_dst[c];
  }
#pragma unroll
  for (int m = 0; m < 4; ++m) {
#pragma unroll
    for (int reg = 0; reg < 4; ++reg) {
      int row = m0 + wm * 64 + m * 16 + g * 4 + reg;
      float ps = 0.f, pd = 0.f;
      if (row < M) {
#pragma unroll
        for (int n = 0; n < 4; ++n) {
          float v = acc[m][n][reg];
          Cb[(size_t)row * 256 + wn * 64 + n * 16 + cl] = f2bf(v);
          ps = fmaf(v, asv[n], ps);
          pd = fmaf(v, adv[n], pd);
        }
      }
#pragma unroll
      for (int off = 1; off < 16; off <<= 1) {
        ps += __shfl_xor(ps, off);
        pd += __shfl_xor(pd, off);
      }
      if (cl == 0 && row < M) {
        atomicAdd(&as_[row], ps);
        atomicAdd(&ad_[row], pd);
      }
    }
  }
}

// ---------------- CSR build ----------------
__global__ void hist_kernel(const int* __restrict__ edge_dst, uint* __restrict__ cnt) {
  int gidx = blockIdx.x * 256 + threadIdx.x;
  if (gidx >= EE / 4) return;
  int4 d = reinterpret_cast<const int4*>(edge_dst)[gidx];
  atomicAdd(&cnt[d.x], 1u);
  atomicAdd(&cnt[d.y], 1u);
  atomicAdd(&cnt[d.z], 1u);
  atomicAdd(&cnt[d.w], 1u);
}

// exclusive scan of (cnt[i]+1)  (+1 = self loop), vectorized 4/thread
__global__ __launch_bounds__(1024) void scan_kernel(const uint* __restrict__ cnt,
                                                    uint* __restrict__ row_ptr,
                                                    uint* __restrict__ nxt, int n) {
  __shared__ uint wsum[16];
  __shared__ uint carry_sh;
  int tid = threadIdx.x, lane = tid & 63, w = tid >> 6;
  if (tid == 0) carry_sh = 0;
  __syncthreads();
  const uint4* c4 = reinterpret_cast<const uint4*>(cnt);
  int ng = n >> 2;
  for (int gb = 0; gb < ng; gb += 1024) {
    int gidx = gb + tid;
    uint4 v;
    if (gidx < ng) v = c4[gidx]; else v = make_uint4(0, 0, 0, 0);
    if (gidx < ng) { v.x += 1; v.y += 1; v.z += 1; v.w += 1; }
    uint t = v.x + v.y + v.z + v.w;
    uint x = t;
#pragma unroll
    for (int off = 1; off < 64; off <<= 1) {
      uint tt = __shfl_up(x, off);
      if (lane >= off) x += tt;
    }
    if (lane == 63) wsum[w] = x;
    __syncthreads();
    uint woff = 0;
    for (int k = 0; k < w; ++k) woff += wsum[k];
    uint carry = carry_sh;
    uint e0 = carry + woff + x - t;
    if (gidx < ng) {
      uint4 rp;
      rp.x = e0;
      rp.y = e0 + v.x;
      rp.z = rp.y + v.y;
      rp.w = rp.z + v.z;
      reinterpret_cast<uint4*>(row_ptr)[gidx] = rp;
      reinterpret_cast<uint4*>(nxt)[gidx] = rp;
    }
    __syncthreads();
    if (tid == 1023) carry_sh = carry + woff + x;
    __syncthreads();
  }
  if (tid == 0) row_ptr[n] = carry_sh;
}

__global__ void scatter_kernel(const int* __restrict__ edge_src, const int* __restrict__ edge_dst,
                               uint* __restrict__ nxt, uint* __restrict__ csr_src) {
  int i = blockIdx.x * 256 + threadIdx.x;
  if (i >= ETOT) return;
  int s = (i < EE) ? edge_src[i] : (i - EE);
  int d = (i < EE) ? edge_dst[i] : (i - EE);
  uint pos = atomicAdd(&nxt[d], 1u);
  csr_src[pos] = (uint)s;
}

// ---------------- GAT aggregation (bf16 gather): out=relu(msg/denom + b) ----------------
__global__ __launch_bounds__(256) void agg_kernel(const u16* __restrict__ h,
                                                  const float* __restrict__ as_,
                                                  const float* __restrict__ ad_,
                                                  const uint* __restrict__ row_ptr,
                                                  const uint* __restrict__ csr_src,
                                                  const float* __restrict__ bias,
                                                  u16* __restrict__ out, int n) {
  int wid = (blockIdx.x * 256 + threadIdx.x) >> 6;
  int lane = threadIdx.x & 63;
  if (wid >= n) return;
  uint start = row_ptr[wid], end = row_ptr[wid + 1];
  float adi = ad_[wid];
  const ushort4* __restrict__ h4 = reinterpret_cast<const ushort4*>(h);
  float ax = 0.f, ay = 0.f, az = 0.f, aw = 0.f;
  float denom = 0.f;
  for (uint base = start; base < end; base += 64) {
    int cnt = (int)(end - base);
    if (cnt > 64) cnt = 64;
    float w = 0.f;
    int s = 0;
    if (lane < cnt) {
      s = (int)csr_src[base + lane];
      float e = as_[s] + adi;
      e = e > 0.f ? e : 0.2f * e;
      w = __expf(e);
    }
    denom += w;
    int j = 0;
    for (; j + 4 <= cnt; j += 4) {
      int s0 = __shfl(s, j), s1 = __shfl(s, j + 1), s2 = __shfl(s, j + 2), s3 = __shfl(s, j + 3);
      float w0 = __shfl(w, j), w1 = __shfl(w, j + 1), w2 = __shfl(w, j + 2), w3 = __shfl(w, j + 3);
      ushort4 v0 = h4[(size_t)s0 * 64 + lane];
      ushort4 v1 = h4[(size_t)s1 * 64 + lane];
      ushort4 v2 = h4[(size_t)s2 * 64 + lane];
      ushort4 v3 = h4[(size_t)s3 * 64 + lane];
      ax = fmaf(w0, bf2f(v0.x), ax); ay = fmaf(w0, bf2f(v0.y), ay);
      az = fmaf(w0, bf2f(v0.z), az); aw = fmaf(w0, bf2f(v0.w), aw);
      ax = fmaf(w1, bf2f(v1.x), ax); ay = fmaf(w1, bf2f(v1.y), ay);
      az = fmaf(w1, bf2f(v1.z), az); aw = fmaf(w1, bf2f(v1.w), aw);
      ax = fmaf(w2, bf2f(v2.x), ax); ay = fmaf(w2, bf2f(v2.y), ay);
      az = fmaf(w2, bf2f(v2.z), az); aw = fmaf(w2, bf2f(v2.w), aw);
      ax = fmaf(w3, bf2f(v3.x), ax); ay = fmaf(w3, bf2f(v3.y), ay);
      az = fmaf(w3, bf2f(v3.z), az); aw = fmaf(w3, bf2f(v3.w), aw);
    }
    for (; j < cnt; ++j) {
      int sj = __shfl(s, j);
      float wj = __shfl(w, j);
      ushort4 v = h4[(size_t)sj * 64 + lane];
      ax = fmaf(wj, bf2f(v.x), ax); ay = fmaf(wj, bf2f(v.y), ay);
      az = fmaf(wj, bf2f(v.z), az); aw = fmaf(wj, bf2f(v.w), aw);
    }
  }
  denom = wred_sum(denom);
  float inv = 1.f / (denom + 1e-16f);
  float4 b = reinterpret_cast<const float4*>(bias)[lane];
  ushort4 o;
  o.x = f2bf(fmaxf(fmaf(ax, inv, b.x), 0.f));
  o.y = f2bf(fmaxf(fmaf(ay, inv, b.y), 0.f));
  o.z = f2bf(fmaxf(fmaf(az, inv, b.z), 0.f));
  o.w = f2bf(fmaxf(fmaf(aw, inv, b.w), 0.f));
  reinterpret_cast<ushort4*>(out)[(size_t)wid * 64 + lane] = o;
}

// ---------------- fused global-attention pooling (unnormalized) ----------------
__global__ __launch_bounds__(256) void pool12_kernel(const u16* __restrict__ h,
                                                     const float* __restrict__ gate_w,
                                                     float* __restrict__ pool_acc,
                                                     float* __restrict__ denom_acc, int n) {
  __shared__ float red[4][256];
  __shared__ float dred[4];
  int lane = threadIdx.x & 63, w = threadIdx.x >> 6;
  float ax = 0.f, ay = 0.f, az = 0.f, aw = 0.f, ds = 0.f;
  float4 gv = reinterpret_cast<const float4*>(gate_w)[lane];
  const ushort4* __restrict__ h4 = reinterpret_cast<const ushort4*>(h);
  int stride = gridDim.x * 4;
  for (int i = blockIdx.x * 4 + w; i < n; i += stride) {
    ushort4 hv = h4[(size_t)i * 64 + lane];
    float fx = bf2f(hv.x), fy = bf2f(hv.y), fz = bf2f(hv.z), fw = bf2f(hv.w);
    float p = wred_sum(fx * gv.x + fy * gv.y + fz * gv.z + fw * gv.w);
    float we = __expf(p);
    ds += we;
    ax = fmaf(we, fx, ax); ay = fmaf(we, fy, ay);
    az = fmaf(we, fz, az); aw = fmaf(we, fw, aw);
  }
  red[w][lane * 4 + 0] = ax;
  red[w][lane * 4 + 1] = ay;
  red[w][lane * 4 + 2] = az;
  red[w][lane * 4 + 3] = aw;
  if (lane == 0) dred[w] = ds;
  __syncthreads();
  if (w == 0) {
#pragma unroll
    for (int c = 0; c < 4; ++c) {
      int f = lane * 4 + c;
      atomicAdd(&pool_acc[f], red[0][f] + red[1][f] + red[2][f] + red[3][f]);
    }
    if (lane == 0) atomicAdd(denom_acc, dred[0] + dred[1] + dred[2] + dred[3]);
  }
}

__global__ void pool3_kernel(const float* __restrict__ pool_acc,
                             const float* __restrict__ denom_acc,
                             float* __restrict__ out) {
  out[threadIdx.x] = pool_acc[threadIdx.x] / denom_acc[0];
}

// ---------------- launch ----------------
extern "C" void kernel_launch(void* const* d_in, const int* in_sizes, int n_in,
                              void* d_out, int out_size, void* d_ws, size_t ws_size,
                              hipStream_t stream) {
  const float* x = (const float*)d_in[0];
  const int* edge = (const int*)d_in[1];
  const float* W0 = (const float*)d_in[2];
  const float* a_src0 = (const float*)d_in[3];
  const float* a_dst0 = (const float*)d_in[4];
  const float* b0 = (const float*)d_in[5];
  const float* W1 = (const float*)d_in[6];
  const float* a_src1 = (const float*)d_in[7];
  const float* a_dst1 = (const float*)d_in[8];
  const float* b1 = (const float*)d_in[9];
  const float* gate_w = (const float*)d_in[10];
  float* out = (float*)d_out;

  char* p = (char*)d_ws;
  size_t off = 0;
  auto take = [&](size_t bytes) -> char* {
    char* r = p + off;
    off = (off + bytes + 255) & ~(size_t)255;
    return r;
  };
  u16* hA = (u16*)take((size_t)NN * 256 * 2);   // bf16 h (GEMM out)
  u16* hB = (u16*)take((size_t)NN * 256 * 2);   // bf16 agg out
  u16* Wt0 = (u16*)take((size_t)256 * 768 * 2);
  u16* Wt1 = (u16*)take((size_t)256 * 256 * 2);
  char* zero_base = p + off;
  float* as0 = (float*)take((size_t)NN * 4);
  float* ad0 = (float*)take((size_t)NN * 4);
  float* as1 = (float*)take((size_t)NN * 4);
  float* ad1 = (float*)take((size_t)NN * 4);
  uint* cnt = (uint*)take((size_t)NN * 4);
  float* pool_acc = (float*)take(256 * 4);
  float* denom_acc = (float*)take(256);
  size_t zero_bytes = (size_t)((p + off) - zero_base);
  uint* row_ptr = (uint*)take((size_t)(NN + 4) * 4);
  uint* nxt = (uint*)take((size_t)NN * 4);
  uint* csr = (uint*)take((size_t)ETOT * 4);

  const int* edge_src = edge;
  const int* edge_dst = edge + EE;

  hipMemsetAsync(zero_base, 0, zero_bytes, stream);

  wt_kernel<<<(768 * 256 + 255) / 256, 256, 0, stream>>>(W0, Wt0, 768, 256);
  wt_kernel<<<(256 * 256 + 255) / 256, 256, 0, stream>>>(W1, Wt1, 256, 256);

  hist_kernel<<<(EE / 4 + 255) / 256, 256, 0, stream>>>(edge_dst, cnt);
  scan_kernel<<<1, 1024, 0, stream>>>(cnt, row_ptr, nxt, NN);
  scatter_kernel<<<(ETOT + 255) / 256, 256, 0, stream>>>(edge_src, edge_dst, nxt, csr);

  const int ggrid = (NN + 127) / 128;
  // layer 0
  gemm_fused<false><<<ggrid, 512, 0, stream>>>(x, Wt0, hA, a_src0, a_dst0, as0, ad0, NN, 768);
  agg_kernel<<<12500, 256, 0, stream>>>(hA, as0, ad0, row_ptr, csr, b0, hB, NN);
  // layer 1 (reuse hA as output of gemm, hB consumed)
  gemm_fused<true><<<ggrid, 512, 0, stream>>>(hB, Wt1, hA, a_src1, a_dst1, as1, ad1, NN, 256);
  agg_kernel<<<12500, 256, 0, stream>>>(hA, as1, ad1, row_ptr, csr, b1, hB, NN);

  pool12_kernel<<<128, 256, 0, stream>>>(hB, gate_w, pool_acc, denom_acc, NN);
  pool3_kernel<<<1, 256, 0, stream>>>(pool_acc, denom_acc, out);
}

// Round 3
// 397.392 us; speedup vs baseline: 2.2765x; 1.4183x over previous
//
#include <hip/hip_runtime.h>

typedef unsigned int uint;
typedef unsigned short u16;

typedef __attribute__((ext_vector_type(8))) short short8;
typedef __attribute__((ext_vector_type(8))) u16 u16x8;
typedef __attribute__((ext_vector_type(4))) float f32x4;

#define NN 50000
#define EE 1600000
#define ETOT (EE + NN)
#define NBUCK 782            // ceil(NN/64)
#define ACHUNK 4096
#define BCAP 8192

__device__ __forceinline__ u16 f2bf(float f) {
  uint u = __builtin_bit_cast(uint, f);
  uint r = u + 0x7fffu + ((u >> 16) & 1u);
  return (u16)(r >> 16);
}
__device__ __forceinline__ float bf2f(u16 h) {
  return __builtin_bit_cast(float, ((uint)h) << 16);
}
__device__ __forceinline__ float wred_sum(float v) {
#pragma unroll
  for (int off = 32; off > 0; off >>= 1) v += __shfl_xor(v, off);
  return v;
}

// ---------------- W transpose + bf16 convert: W[K][N] -> Wt[N][K] ----------------
__global__ void wt_kernel(const float* __restrict__ W, u16* __restrict__ Wt, int K, int N) {
  int i = blockIdx.x * 256 + threadIdx.x;
  if (i >= K * N) return;
  int k = i / N, n = i % N;
  Wt[(size_t)n * K + k] = f2bf(W[i]);
}

// ---------------- GEMM + fused alpha epilogue ----------------
template <bool ABF16>
__global__ __launch_bounds__(512) void gemm_fused(const void* __restrict__ Avoid,
                                                  const u16* __restrict__ Bt,
                                                  u16* __restrict__ Cb,
                                                  const float* __restrict__ a_src,
                                                  const float* __restrict__ a_dst,
                                                  float* __restrict__ as_,
                                                  float* __restrict__ ad_,
                                                  int M, int K) {
  __shared__ __align__(16) u16 As[128 * 64];
  __shared__ __align__(16) u16 Bs[256 * 64];
  const int m0 = blockIdx.x * 128;
  const int tid = threadIdx.x;
  const int lane = tid & 63;
  const int wv = tid >> 6;
  const int wm = wv >> 2, wn = wv & 3;

  f32x4 acc[4][4] = {};

  const int sr = tid >> 2;
  const int skc = (tid & 3) * 16;
  const int br = tid >> 1;
  const int bk = (tid & 1) * 32;

  for (int k0 = 0; k0 < K; k0 += 64) {
    {
      int grow = m0 + sr;
      if constexpr (!ABF16) {
        const float* A = (const float*)Avoid;
        float4 f[4];
        if (grow < M) {
          const float4* src = reinterpret_cast<const float4*>(A + (size_t)grow * K + k0 + skc);
#pragma unroll
          for (int i = 0; i < 4; ++i) f[i] = src[i];
        } else {
#pragma unroll
          for (int i = 0; i < 4; ++i) f[i] = make_float4(0.f, 0.f, 0.f, 0.f);
        }
#pragma unroll
        for (int i = 0; i < 2; ++i) {
          u16x8 v;
          v[0] = f2bf(f[2 * i].x); v[1] = f2bf(f[2 * i].y);
          v[2] = f2bf(f[2 * i].z); v[3] = f2bf(f[2 * i].w);
          v[4] = f2bf(f[2 * i + 1].x); v[5] = f2bf(f[2 * i + 1].y);
          v[6] = f2bf(f[2 * i + 1].z); v[7] = f2bf(f[2 * i + 1].w);
          int k = skc + i * 8;
          int idx = (sr << 6) + (k ^ ((sr & 7) << 3));
          *reinterpret_cast<u16x8*>(&As[idx]) = v;
        }
      } else {
        const u16* A = (const u16*)Avoid;
        u16x8 v[2];
        if (grow < M) {
          const u16x8* src = reinterpret_cast<const u16x8*>(A + (size_t)grow * K + k0 + skc);
          v[0] = src[0]; v[1] = src[1];
        } else {
          v[0] = (u16x8)0; v[1] = (u16x8)0;
        }
#pragma unroll
        for (int i = 0; i < 2; ++i) {
          int k = skc + i * 8;
          int idx = (sr << 6) + (k ^ ((sr & 7) << 3));
          *reinterpret_cast<u16x8*>(&As[idx]) = v[i];
        }
      }
    }
    {
      const u16x8* src = reinterpret_cast<const u16x8*>(Bt + (size_t)br * K + k0 + bk);
#pragma unroll
      for (int i = 0; i < 4; ++i) {
        u16x8 v = src[i];
        int k = bk + i * 8;
        int idx = (br << 6) + (k ^ ((br & 7) << 3));
        *reinterpret_cast<u16x8*>(&Bs[idx]) = v;
      }
    }
    __syncthreads();
#pragma unroll
    for (int kk = 0; kk < 2; ++kk) {
      short8 af[4], bfr[4];
      const int kb = kk * 32 + (lane >> 4) * 8;
#pragma unroll
      for (int m = 0; m < 4; ++m) {
        int r = wm * 64 + m * 16 + (lane & 15);
        int idx = (r << 6) + (kb ^ ((r & 7) << 3));
        af[m] = *reinterpret_cast<const short8*>(&As[idx]);
      }
#pragma unroll
      for (int n = 0; n < 4; ++n) {
        int c = wn * 64 + n * 16 + (lane & 15);
        int idx = (c << 6) + (kb ^ ((c & 7) << 3));
        bfr[n] = *reinterpret_cast<const short8*>(&Bs[idx]);
      }
#pragma unroll
      for (int m = 0; m < 4; ++m)
#pragma unroll
        for (int n = 0; n < 4; ++n)
          acc[m][n] = __builtin_amdgcn_mfma_f32_16x16x32_bf16(af[m], bfr[n], acc[m][n], 0, 0, 0);
    }
    __syncthreads();
  }

  const int g = lane >> 4;
  const int cl = lane & 15;
  float asv[4], adv[4];
#pragma unroll
  for (int n = 0; n < 4; ++n) {
    int c = wn * 64 + n * 16 + cl;
    asv[n] = a_src[c];
    adv[n] = a_dst[c];
  }
#pragma unroll
  for (int m = 0; m < 4; ++m) {
#pragma unroll
    for (int reg = 0; reg < 4; ++reg) {
      int row = m0 + wm * 64 + m * 16 + g * 4 + reg;
      float ps = 0.f, pd = 0.f;
      if (row < M) {
#pragma unroll
        for (int n = 0; n < 4; ++n) {
          float v = acc[m][n][reg];
          Cb[(size_t)row * 256 + wn * 64 + n * 16 + cl] = f2bf(v);
          ps = fmaf(v, asv[n], ps);
          pd = fmaf(v, adv[n], pd);
        }
      }
#pragma unroll
      for (int off = 1; off < 16; off <<= 1) {
        ps += __shfl_xor(ps, off);
        pd += __shfl_xor(pd, off);
      }
      if (cl == 0 && row < M) {
        atomicAdd(&as_[row], ps);
        atomicAdd(&ad_[row], pd);
      }
    }
  }
}

// ---------------- CSR build: two-level counting sort ----------------
// Pass 0: bucket histogram (bucket = dst>>6), LDS-privatized
__global__ __launch_bounds__(256) void histb_kernel(const int* __restrict__ edge_dst,
                                                    uint* __restrict__ bcnt) {
  __shared__ uint h[NBUCK];
  for (int i = threadIdx.x; i < NBUCK; i += 256) h[i] = 0;
  __syncthreads();
  int stride = gridDim.x * 256;
  for (int i = blockIdx.x * 256 + threadIdx.x; i < EE / 4; i += stride) {
    int4 d = reinterpret_cast<const int4*>(edge_dst)[i];
    atomicAdd(&h[d.x >> 6], 1u);
    atomicAdd(&h[d.y >> 6], 1u);
    atomicAdd(&h[d.z >> 6], 1u);
    atomicAdd(&h[d.w >> 6], 1u);
  }
  __syncthreads();
  for (int i = threadIdx.x; i < NBUCK; i += 256) {
    uint v = h[i];
    if (v) atomicAdd(&bcnt[i], v);
  }
}

// Pass 1: exclusive scan of (bcnt[b] + selfloops(b)) -> bptr, bnxt
__global__ __launch_bounds__(1024) void scanb_kernel(const uint* __restrict__ bcnt,
                                                     uint* __restrict__ bptr,
                                                     uint* __restrict__ bnxt) {
  __shared__ uint wsum[16];
  int tid = threadIdx.x, lane = tid & 63, w = tid >> 6;
  uint v = 0;
  if (tid < NBUCK) {
    int self = NN - tid * 64;
    if (self > 64) self = 64;
    v = bcnt[tid] + (uint)self;
  }
  uint x = v;
#pragma unroll
  for (int off = 1; off < 64; off <<= 1) {
    uint t = __shfl_up(x, off);
    if (lane >= off) x += t;
  }
  if (lane == 63) wsum[w] = x;
  __syncthreads();
  uint woff = 0;
  for (int k = 0; k < w; ++k) woff += wsum[k];
  uint excl = woff + x - v;
  if (tid < NBUCK) { bptr[tid] = excl; bnxt[tid] = excl; }
  if (tid == NBUCK) bptr[NBUCK] = excl;
}

// Pass 2: scatter packed (dstlow<<16|src) into bucket regions (privatized reservation)
__global__ __launch_bounds__(256) void bucket_scatter(const int* __restrict__ esrc,
                                                      const int* __restrict__ edst,
                                                      uint* __restrict__ bnxt,
                                                      uint* __restrict__ tmp) {
  __shared__ uint lh[NBUCK];
  int base = blockIdx.x * ACHUNK;
  int nE = ETOT - base; if (nE > ACHUNK) nE = ACHUNK;
  for (int i = threadIdx.x; i < NBUCK; i += 256) lh[i] = 0;
  __syncthreads();
  for (int k = threadIdx.x; k < nE; k += 256) {
    int e = base + k;
    int d = (e < EE) ? edst[e] : (e - EE);
    atomicAdd(&lh[d >> 6], 1u);
  }
  __syncthreads();
  for (int i = threadIdx.x; i < NBUCK; i += 256) {
    uint c = lh[i];
    lh[i] = c ? atomicAdd(&bnxt[i], c) : 0u;
  }
  __syncthreads();
  for (int k = threadIdx.x; k < nE; k += 256) {
    int e = base + k;
    int s, d;
    if (e < EE) { s = esrc[e]; d = edst[e]; } else { s = e - EE; d = s; }
    uint pos = atomicAdd(&lh[d >> 6], 1u);
    tmp[pos] = ((uint)(d & 63) << 16) | (uint)s;
  }
}

// Pass 3: per-bucket 64-bin counting sort -> final csr + row_ptr
__global__ __launch_bounds__(256) void bucket_sort(const uint* __restrict__ tmp,
                                                   const uint* __restrict__ bptr,
                                                   uint* __restrict__ row_ptr,
                                                   uint* __restrict__ csr) {
  __shared__ uint lh[64];
  __shared__ uint buf[BCAP];
  int b = blockIdx.x;
  uint s0 = bptr[b], s1 = bptr[b + 1];
  int cnt = (int)(s1 - s0);
  int tid = threadIdx.x;
  if (tid < 64) lh[tid] = 0;
  __syncthreads();
  for (int i = tid; i < cnt; i += 256) {
    uint v = tmp[s0 + i];
    buf[i] = v;
    atomicAdd(&lh[v >> 16], 1u);
  }
  __syncthreads();
  if (tid < 64) {
    uint v = lh[tid];
    uint x = v;
#pragma unroll
    for (int off = 1; off < 64; off <<= 1) {
      uint t = __shfl_up(x, off);
      if (tid >= off) x += t;
    }
    uint pos = s0 + x - v;
    int d = b * 64 + tid;
    if (d < NN) row_ptr[d] = pos;
    lh[tid] = pos;
    if (b == NBUCK - 1 && tid == 0) row_ptr[NN] = s1;
  }
  __syncthreads();
  for (int i = tid; i < cnt; i += 256) {
    uint v = buf[i];
    uint pos = atomicAdd(&lh[v >> 16], 1u);
    csr[pos] = v & 0xFFFFu;
  }
}

// ---------------- GAT aggregation (bf16 gather): out=relu(msg/denom + b) ----------------
__global__ __launch_bounds__(256) void agg_kernel(const u16* __restrict__ h,
                                                  const float* __restrict__ as_,
                                                  const float* __restrict__ ad_,
                                                  const uint* __restrict__ row_ptr,
                                                  const uint* __restrict__ csr_src,
                                                  const float* __restrict__ bias,
                                                  u16* __restrict__ out, int n) {
  int wid = (blockIdx.x * 256 + threadIdx.x) >> 6;
  int lane = threadIdx.x & 63;
  if (wid >= n) return;
  uint start = row_ptr[wid], end = row_ptr[wid + 1];
  float adi = ad_[wid];
  const ushort4* __restrict__ h4 = reinterpret_cast<const ushort4*>(h);
  float ax = 0.f, ay = 0.f, az = 0.f, aw = 0.f;
  float denom = 0.f;
  for (uint base = start; base < end; base += 64) {
    int cnt = (int)(end - base);
    if (cnt > 64) cnt = 64;
    float w = 0.f;
    int s = 0;
    if (lane < cnt) {
      s = (int)csr_src[base + lane];
      float e = as_[s] + adi;
      e = e > 0.f ? e : 0.2f * e;
      w = __expf(e);
    }
    denom += w;
    int j = 0;
    for (; j + 4 <= cnt; j += 4) {
      int s0 = __shfl(s, j), s1 = __shfl(s, j + 1), s2 = __shfl(s, j + 2), s3 = __shfl(s, j + 3);
      float w0 = __shfl(w, j), w1 = __shfl(w, j + 1), w2 = __shfl(w, j + 2), w3 = __shfl(w, j + 3);
      ushort4 v0 = h4[(size_t)s0 * 64 + lane];
      ushort4 v1 = h4[(size_t)s1 * 64 + lane];
      ushort4 v2 = h4[(size_t)s2 * 64 + lane];
      ushort4 v3 = h4[(size_t)s3 * 64 + lane];
      ax = fmaf(w0, bf2f(v0.x), ax); ay = fmaf(w0, bf2f(v0.y), ay);
      az = fmaf(w0, bf2f(v0.z), az); aw = fmaf(w0, bf2f(v0.w), aw);
      ax = fmaf(w1, bf2f(v1.x), ax); ay = fmaf(w1, bf2f(v1.y), ay);
      az = fmaf(w1, bf2f(v1.z), az); aw = fmaf(w1, bf2f(v1.w), aw);
      ax = fmaf(w2, bf2f(v2.x), ax); ay = fmaf(w2, bf2f(v2.y), ay);
      az = fmaf(w2, bf2f(v2.z), az); aw = fmaf(w2, bf2f(v2.w), aw);
      ax = fmaf(w3, bf2f(v3.x), ax); ay = fmaf(w3, bf2f(v3.y), ay);
      az = fmaf(w3, bf2f(v3.z), az); aw = fmaf(w3, bf2f(v3.w), aw);
    }
    for (; j < cnt; ++j) {
      int sj = __shfl(s, j);
      float wj = __shfl(w, j);
      ushort4 v = h4[(size_t)sj * 64 + lane];
      ax = fmaf(wj, bf2f(v.x), ax); ay = fmaf(wj, bf2f(v.y), ay);
      az = fmaf(wj, bf2f(v.z), az); aw = fmaf(wj, bf2f(v.w), aw);
    }
  }
  denom = wred_sum(denom);
  float inv = 1.f / (denom + 1e-16f);
  float4 b = reinterpret_cast<const float4*>(bias)[lane];
  ushort4 o;
  o.x = f2bf(fmaxf(fmaf(ax, inv, b.x), 0.f));
  o.y = f2bf(fmaxf(fmaf(ay, inv, b.y), 0.f));
  o.z = f2bf(fmaxf(fmaf(az, inv, b.z), 0.f));
  o.w = f2bf(fmaxf(fmaf(aw, inv, b.w), 0.f));
  reinterpret_cast<ushort4*>(out)[(size_t)wid * 64 + lane] = o;
}

// ---------------- fused global-attention pooling (unnormalized) ----------------
__global__ __launch_bounds__(256) void pool12_kernel(const u16* __restrict__ h,
                                                     const float* __restrict__ gate_w,
                                                     float* __restrict__ pool_acc,
                                                     float* __restrict__ denom_acc, int n) {
  __shared__ float red[4][256];
  __shared__ float dred[4];
  int lane = threadIdx.x & 63, w = threadIdx.x >> 6;
  float ax = 0.f, ay = 0.f, az = 0.f, aw = 0.f, ds = 0.f;
  float4 gv = reinterpret_cast<const float4*>(gate_w)[lane];
  const ushort4* __restrict__ h4 = reinterpret_cast<const ushort4*>(h);
  int stride = gridDim.x * 4;
  for (int i = blockIdx.x * 4 + w; i < n; i += stride) {
    ushort4 hv = h4[(size_t)i * 64 + lane];
    float fx = bf2f(hv.x), fy = bf2f(hv.y), fz = bf2f(hv.z), fw = bf2f(hv.w);
    float p = wred_sum(fx * gv.x + fy * gv.y + fz * gv.z + fw * gv.w);
    float we = __expf(p);
    ds += we;
    ax = fmaf(we, fx, ax); ay = fmaf(we, fy, ay);
    az = fmaf(we, fz, az); aw = fmaf(we, fw, aw);
  }
  red[w][lane * 4 + 0] = ax;
  red[w][lane * 4 + 1] = ay;
  red[w][lane * 4 + 2] = az;
  red[w][lane * 4 + 3] = aw;
  if (lane == 0) dred[w] = ds;
  __syncthreads();
  if (w == 0) {
#pragma unroll
    for (int c = 0; c < 4; ++c) {
      int f = lane * 4 + c;
      atomicAdd(&pool_acc[f], red[0][f] + red[1][f] + red[2][f] + red[3][f]);
    }
    if (lane == 0) atomicAdd(denom_acc, dred[0] + dred[1] + dred[2] + dred[3]);
  }
}

__global__ void pool3_kernel(const float* __restrict__ pool_acc,
                             const float* __restrict__ denom_acc,
                             float* __restrict__ out) {
  out[threadIdx.x] = pool_acc[threadIdx.x] / denom_acc[0];
}

// ---------------- launch ----------------
extern "C" void kernel_launch(void* const* d_in, const int* in_sizes, int n_in,
                              void* d_out, int out_size, void* d_ws, size_t ws_size,
                              hipStream_t stream) {
  const float* x = (const float*)d_in[0];
  const int* edge = (const int*)d_in[1];
  const float* W0 = (const float*)d_in[2];
  const float* a_src0 = (const float*)d_in[3];
  const float* a_dst0 = (const float*)d_in[4];
  const float* b0 = (const float*)d_in[5];
  const float* W1 = (const float*)d_in[6];
  const float* a_src1 = (const float*)d_in[7];
  const float* a_dst1 = (const float*)d_in[8];
  const float* b1 = (const float*)d_in[9];
  const float* gate_w = (const float*)d_in[10];
  float* out = (float*)d_out;

  char* p = (char*)d_ws;
  size_t off = 0;
  auto take = [&](size_t bytes) -> char* {
    char* r = p + off;
    off = (off + bytes + 255) & ~(size_t)255;
    return r;
  };
  u16* hA = (u16*)take((size_t)NN * 256 * 2);
  u16* hB = (u16*)take((size_t)NN * 256 * 2);
  u16* Wt0 = (u16*)take((size_t)256 * 768 * 2);
  u16* Wt1 = (u16*)take((size_t)256 * 256 * 2);
  char* zero_base = p + off;
  float* as0 = (float*)take((size_t)NN * 4);
  float* ad0 = (float*)take((size_t)NN * 4);
  float* as1 = (float*)take((size_t)NN * 4);
  float* ad1 = (float*)take((size_t)NN * 4);
  uint* bcnt = (uint*)take((size_t)NBUCK * 4);
  float* pool_acc = (float*)take(256 * 4);
  float* denom_acc = (float*)take(256);
  size_t zero_bytes = (size_t)((p + off) - zero_base);
  uint* bptr = (uint*)take((size_t)(NBUCK + 1) * 4);
  uint* bnxt = (uint*)take((size_t)NBUCK * 4);
  uint* row_ptr = (uint*)take((size_t)(NN + 1) * 4);
  uint* tmp = (uint*)take((size_t)ETOT * 4);
  uint* csr = (uint*)take((size_t)ETOT * 4);

  const int* edge_src = edge;
  const int* edge_dst = edge + EE;

  hipMemsetAsync(zero_base, 0, zero_bytes, stream);

  wt_kernel<<<(768 * 256 + 255) / 256, 256, 0, stream>>>(W0, Wt0, 768, 256);
  wt_kernel<<<(256 * 256 + 255) / 256, 256, 0, stream>>>(W1, Wt1, 256, 256);

  histb_kernel<<<256, 256, 0, stream>>>(edge_dst, bcnt);
  scanb_kernel<<<1, 1024, 0, stream>>>(bcnt, bptr, bnxt);
  bucket_scatter<<<(ETOT + ACHUNK - 1) / ACHUNK, 256, 0, stream>>>(edge_src, edge_dst, bnxt, tmp);
  bucket_sort<<<NBUCK, 256, 0, stream>>>(tmp, bptr, row_ptr, csr);

  const int ggrid = (NN + 127) / 128;
  gemm_fused<false><<<ggrid, 512, 0, stream>>>(x, Wt0, hA, a_src0, a_dst0, as0, ad0, NN, 768);
  agg_kernel<<<12500, 256, 0, stream>>>(hA, as0, ad0, row_ptr, csr, b0, hB, NN);
  gemm_fused<true><<<ggrid, 512, 0, stream>>>(hB, Wt1, hA, a_src1, a_dst1, as1, ad1, NN, 256);
  agg_kernel<<<12500, 256, 0, stream>>>(hA, as1, ad1, row_ptr, csr, b1, hB, NN);

  pool12_kernel<<<128, 256, 0, stream>>>(hB, gate_w, pool_acc, denom_acc, NN);
  pool3_kernel<<<1, 256, 0, stream>>>(pool_acc, denom_acc, out);
}

// Round 4
// 301.818 us; speedup vs baseline: 2.9974x; 1.3167x over previous
//
#include <hip/hip_runtime.h>

typedef unsigned int uint;
typedef unsigned short u16;
typedef unsigned char u8;

typedef __attribute__((ext_vector_type(8))) short short8;
typedef __attribute__((ext_vector_type(8))) u16 u16x8;
typedef __attribute__((ext_vector_type(4))) float f32x4;
typedef __attribute__((ext_vector_type(2))) float f32x2;

#define NN 50000
#define EE 1600000
#define ETOT (EE + NN)
#define NBUCK 782            // ceil(NN/64)
#define ACHUNK 4096
#define BCAP 8192

__device__ __forceinline__ u16 f2bf(float f) {
  uint u = __builtin_bit_cast(uint, f);
  uint r = u + 0x7fffu + ((u >> 16) & 1u);
  return (u16)(r >> 16);
}
__device__ __forceinline__ float bf2f(u16 h) {
  return __builtin_bit_cast(float, ((uint)h) << 16);
}
__device__ __forceinline__ u8 f2fp8(float f) {
  int t = __builtin_amdgcn_cvt_pk_fp8_f32(f, f, 0, false);
  return (u8)(t & 0xff);
}
__device__ __forceinline__ float wred_sum(float v) {
#pragma unroll
  for (int off = 32; off > 0; off >>= 1) v += __shfl_xor(v, off);
  return v;
}

// ---------------- W transpose + bf16 convert: W[K][N] -> Wt[N][K] ----------------
__global__ void wt_kernel(const float* __restrict__ W, u16* __restrict__ Wt, int K, int N) {
  int i = blockIdx.x * 256 + threadIdx.x;
  if (i >= K * N) return;
  int k = i / N, n = i % N;
  Wt[(size_t)n * K + k] = f2bf(W[i]);
}

// ---------------- GEMM + fused alpha epilogue; C written as fp8 e4m3 ----------------
template <bool ABF16>
__global__ __launch_bounds__(512) void gemm_fused(const void* __restrict__ Avoid,
                                                  const u16* __restrict__ Bt,
                                                  u8* __restrict__ C8,
                                                  const float* __restrict__ a_src,
                                                  const float* __restrict__ a_dst,
                                                  float* __restrict__ as_,
                                                  float* __restrict__ ad_,
                                                  int M, int K) {
  __shared__ __align__(16) u16 As[128 * 64];
  __shared__ __align__(16) u16 Bs[256 * 64];
  const int m0 = blockIdx.x * 128;
  const int tid = threadIdx.x;
  const int lane = tid & 63;
  const int wv = tid >> 6;
  const int wm = wv >> 2, wn = wv & 3;

  f32x4 acc[4][4] = {};

  const int sr = tid >> 2;
  const int skc = (tid & 3) * 16;
  const int br = tid >> 1;
  const int bk = (tid & 1) * 32;

  for (int k0 = 0; k0 < K; k0 += 64) {
    {
      int grow = m0 + sr;
      if constexpr (!ABF16) {
        const float* A = (const float*)Avoid;
        float4 f[4];
        if (grow < M) {
          const float4* src = reinterpret_cast<const float4*>(A + (size_t)grow * K + k0 + skc);
#pragma unroll
          for (int i = 0; i < 4; ++i) f[i] = src[i];
        } else {
#pragma unroll
          for (int i = 0; i < 4; ++i) f[i] = make_float4(0.f, 0.f, 0.f, 0.f);
        }
#pragma unroll
        for (int i = 0; i < 2; ++i) {
          u16x8 v;
          v[0] = f2bf(f[2 * i].x); v[1] = f2bf(f[2 * i].y);
          v[2] = f2bf(f[2 * i].z); v[3] = f2bf(f[2 * i].w);
          v[4] = f2bf(f[2 * i + 1].x); v[5] = f2bf(f[2 * i + 1].y);
          v[6] = f2bf(f[2 * i + 1].z); v[7] = f2bf(f[2 * i + 1].w);
          int k = skc + i * 8;
          int idx = (sr << 6) + (k ^ ((sr & 7) << 3));
          *reinterpret_cast<u16x8*>(&As[idx]) = v;
        }
      } else {
        const u16* A = (const u16*)Avoid;
        u16x8 v[2];
        if (grow < M) {
          const u16x8* src = reinterpret_cast<const u16x8*>(A + (size_t)grow * K + k0 + skc);
          v[0] = src[0]; v[1] = src[1];
        } else {
          v[0] = (u16x8)0; v[1] = (u16x8)0;
        }
#pragma unroll
        for (int i = 0; i < 2; ++i) {
          int k = skc + i * 8;
          int idx = (sr << 6) + (k ^ ((sr & 7) << 3));
          *reinterpret_cast<u16x8*>(&As[idx]) = v[i];
        }
      }
    }
    {
      const u16x8* src = reinterpret_cast<const u16x8*>(Bt + (size_t)br * K + k0 + bk);
#pragma unroll
      for (int i = 0; i < 4; ++i) {
        u16x8 v = src[i];
        int k = bk + i * 8;
        int idx = (br << 6) + (k ^ ((br & 7) << 3));
        *reinterpret_cast<u16x8*>(&Bs[idx]) = v;
      }
    }
    __syncthreads();
#pragma unroll
    for (int kk = 0; kk < 2; ++kk) {
      short8 af[4], bfr[4];
      const int kb = kk * 32 + (lane >> 4) * 8;
#pragma unroll
      for (int m = 0; m < 4; ++m) {
        int r = wm * 64 + m * 16 + (lane & 15);
        int idx = (r << 6) + (kb ^ ((r & 7) << 3));
        af[m] = *reinterpret_cast<const short8*>(&As[idx]);
      }
#pragma unroll
      for (int n = 0; n < 4; ++n) {
        int c = wn * 64 + n * 16 + (lane & 15);
        int idx = (c << 6) + (kb ^ ((c & 7) << 3));
        bfr[n] = *reinterpret_cast<const short8*>(&Bs[idx]);
      }
#pragma unroll
      for (int m = 0; m < 4; ++m)
#pragma unroll
        for (int n = 0; n < 4; ++n)
          acc[m][n] = __builtin_amdgcn_mfma_f32_16x16x32_bf16(af[m], bfr[n], acc[m][n], 0, 0, 0);
    }
    __syncthreads();
  }

  const int g = lane >> 4;
  const int cl = lane & 15;
  float asv[4], adv[4];
#pragma unroll
  for (int n = 0; n < 4; ++n) {
    int c = wn * 64 + n * 16 + cl;
    asv[n] = a_src[c];
    adv[n] = a_dst[c];
  }
#pragma unroll
  for (int m = 0; m < 4; ++m) {
#pragma unroll
    for (int reg = 0; reg < 4; ++reg) {
      int row = m0 + wm * 64 + m * 16 + g * 4 + reg;
      float ps = 0.f, pd = 0.f;
      if (row < M) {
#pragma unroll
        for (int n = 0; n < 4; ++n) {
          float v = acc[m][n][reg];
          C8[(size_t)row * 256 + wn * 64 + n * 16 + cl] = f2fp8(v);
          ps = fmaf(v, asv[n], ps);
          pd = fmaf(v, adv[n], pd);
        }
      }
#pragma unroll
      for (int off = 1; off < 16; off <<= 1) {
        ps += __shfl_xor(ps, off);
        pd += __shfl_xor(pd, off);
      }
      if (cl == 0 && row < M) {
        atomicAdd(&as_[row], ps);
        atomicAdd(&ad_[row], pd);
      }
    }
  }
}

// ---------------- CSR build: two-level counting sort ----------------
__global__ __launch_bounds__(256) void histb_kernel(const int* __restrict__ edge_dst,
                                                    uint* __restrict__ bcnt) {
  __shared__ uint h[NBUCK];
  for (int i = threadIdx.x; i < NBUCK; i += 256) h[i] = 0;
  __syncthreads();
  int stride = gridDim.x * 256;
  for (int i = blockIdx.x * 256 + threadIdx.x; i < EE / 4; i += stride) {
    int4 d = reinterpret_cast<const int4*>(edge_dst)[i];
    atomicAdd(&h[d.x >> 6], 1u);
    atomicAdd(&h[d.y >> 6], 1u);
    atomicAdd(&h[d.z >> 6], 1u);
    atomicAdd(&h[d.w >> 6], 1u);
  }
  __syncthreads();
  for (int i = threadIdx.x; i < NBUCK; i += 256) {
    uint v = h[i];
    if (v) atomicAdd(&bcnt[i], v);
  }
}

__global__ __launch_bounds__(1024) void scanb_kernel(const uint* __restrict__ bcnt,
                                                     uint* __restrict__ bptr,
                                                     uint* __restrict__ bnxt) {
  __shared__ uint wsum[16];
  int tid = threadIdx.x, lane = tid & 63, w = tid >> 6;
  uint v = 0;
  if (tid < NBUCK) {
    int self = NN - tid * 64;
    if (self > 64) self = 64;
    v = bcnt[tid] + (uint)self;
  }
  uint x = v;
#pragma unroll
  for (int off = 1; off < 64; off <<= 1) {
    uint t = __shfl_up(x, off);
    if (lane >= off) x += t;
  }
  if (lane == 63) wsum[w] = x;
  __syncthreads();
  uint woff = 0;
  for (int k = 0; k < w; ++k) woff += wsum[k];
  uint excl = woff + x - v;
  if (tid < NBUCK) { bptr[tid] = excl; bnxt[tid] = excl; }
  if (tid == NBUCK) bptr[NBUCK] = excl;
}

__global__ __launch_bounds__(256) void bucket_scatter(const int* __restrict__ esrc,
                                                      const int* __restrict__ edst,
                                                      uint* __restrict__ bnxt,
                                                      uint* __restrict__ tmp) {
  __shared__ uint lh[NBUCK];
  int base = blockIdx.x * ACHUNK;
  int nE = ETOT - base; if (nE > ACHUNK) nE = ACHUNK;
  for (int i = threadIdx.x; i < NBUCK; i += 256) lh[i] = 0;
  __syncthreads();
  for (int k = threadIdx.x; k < nE; k += 256) {
    int e = base + k;
    int d = (e < EE) ? edst[e] : (e - EE);
    atomicAdd(&lh[d >> 6], 1u);
  }
  __syncthreads();
  for (int i = threadIdx.x; i < NBUCK; i += 256) {
    uint c = lh[i];
    lh[i] = c ? atomicAdd(&bnxt[i], c) : 0u;
  }
  __syncthreads();
  for (int k = threadIdx.x; k < nE; k += 256) {
    int e = base + k;
    int s, d;
    if (e < EE) { s = esrc[e]; d = edst[e]; } else { s = e - EE; d = s; }
    uint pos = atomicAdd(&lh[d >> 6], 1u);
    tmp[pos] = ((uint)(d & 63) << 16) | (uint)s;
  }
}

__global__ __launch_bounds__(256) void bucket_sort(const uint* __restrict__ tmp,
                                                   const uint* __restrict__ bptr,
                                                   uint* __restrict__ row_ptr,
                                                   uint* __restrict__ csr) {
  __shared__ uint lh[64];
  __shared__ uint buf[BCAP];
  int b = blockIdx.x;
  uint s0 = bptr[b], s1 = bptr[b + 1];
  int cnt = (int)(s1 - s0);
  int tid = threadIdx.x;
  if (tid < 64) lh[tid] = 0;
  __syncthreads();
  for (int i = tid; i < cnt; i += 256) {
    uint v = tmp[s0 + i];
    buf[i] = v;
    atomicAdd(&lh[v >> 16], 1u);
  }
  __syncthreads();
  if (tid < 64) {
    uint v = lh[tid];
    uint x = v;
#pragma unroll
    for (int off = 1; off < 64; off <<= 1) {
      uint t = __shfl_up(x, off);
      if (tid >= off) x += t;
    }
    uint pos = s0 + x - v;
    int d = b * 64 + tid;
    if (d < NN) row_ptr[d] = pos;
    lh[tid] = pos;
    if (b == NBUCK - 1 && tid == 0) row_ptr[NN] = s1;
  }
  __syncthreads();
  for (int i = tid; i < cnt; i += 256) {
    uint v = buf[i];
    uint pos = atomicAdd(&lh[v >> 16], 1u);
    csr[pos] = v & 0xFFFFu;
  }
}

// ---------------- GAT aggregation (fp8 gather): out=relu(msg/denom + b), bf16 ----------------
__global__ __launch_bounds__(256) void agg_kernel(const uint* __restrict__ h8,
                                                  const float* __restrict__ as_,
                                                  const float* __restrict__ ad_,
                                                  const uint* __restrict__ row_ptr,
                                                  const uint* __restrict__ csr_src,
                                                  const float* __restrict__ bias,
                                                  u16* __restrict__ out, int n) {
  int wid = (blockIdx.x * 256 + threadIdx.x) >> 6;
  int lane = threadIdx.x & 63;
  if (wid >= n) return;
  uint start = row_ptr[wid], end = row_ptr[wid + 1];
  float adi = ad_[wid];
  float ax = 0.f, ay = 0.f, az = 0.f, aw = 0.f;
  float denom = 0.f;
  for (uint base = start; base < end; base += 64) {
    int cnt = (int)(end - base);
    if (cnt > 64) cnt = 64;
    float w = 0.f;
    int s = 0;
    if (lane < cnt) {
      s = (int)csr_src[base + lane];
      float e = as_[s] + adi;
      e = e > 0.f ? e : 0.2f * e;
      w = __expf(e);
    }
    denom += w;
    int j = 0;
    for (; j + 8 <= cnt; j += 8) {
      uint v[8];
      float ww[8];
#pragma unroll
      for (int q = 0; q < 8; ++q) {
        int sq = __shfl(s, j + q);
        ww[q] = __shfl(w, j + q);
        v[q] = h8[(size_t)sq * 64 + lane];
      }
#pragma unroll
      for (int q = 0; q < 8; ++q) {
        f32x2 lo = __builtin_amdgcn_cvt_pk_f32_fp8(v[q], false);
        f32x2 hi = __builtin_amdgcn_cvt_pk_f32_fp8(v[q], true);
        ax = fmaf(ww[q], lo.x, ax); ay = fmaf(ww[q], lo.y, ay);
        az = fmaf(ww[q], hi.x, az); aw = fmaf(ww[q], hi.y, aw);
      }
    }
    for (; j < cnt; ++j) {
      int sj = __shfl(s, j);
      float wj = __shfl(w, j);
      uint v = h8[(size_t)sj * 64 + lane];
      f32x2 lo = __builtin_amdgcn_cvt_pk_f32_fp8(v, false);
      f32x2 hi = __builtin_amdgcn_cvt_pk_f32_fp8(v, true);
      ax = fmaf(wj, lo.x, ax); ay = fmaf(wj, lo.y, ay);
      az = fmaf(wj, hi.x, az); aw = fmaf(wj, hi.y, aw);
    }
  }
  denom = wred_sum(denom);
  float inv = 1.f / (denom + 1e-16f);
  float4 b = reinterpret_cast<const float4*>(bias)[lane];
  ushort4 o;
  o.x = f2bf(fmaxf(fmaf(ax, inv, b.x), 0.f));
  o.y = f2bf(fmaxf(fmaf(ay, inv, b.y), 0.f));
  o.z = f2bf(fmaxf(fmaf(az, inv, b.z), 0.f));
  o.w = f2bf(fmaxf(fmaf(aw, inv, b.w), 0.f));
  reinterpret_cast<ushort4*>(out)[(size_t)wid * 64 + lane] = o;
}

// ---------------- fused global-attention pooling (unnormalized) ----------------
__global__ __launch_bounds__(256) void pool12_kernel(const u16* __restrict__ h,
                                                     const float* __restrict__ gate_w,
                                                     float* __restrict__ pool_acc,
                                                     float* __restrict__ denom_acc, int n) {
  __shared__ float red[4][256];
  __shared__ float dred[4];
  int lane = threadIdx.x & 63, w = threadIdx.x >> 6;
  float ax = 0.f, ay = 0.f, az = 0.f, aw = 0.f, ds = 0.f;
  float4 gv = reinterpret_cast<const float4*>(gate_w)[lane];
  const ushort4* __restrict__ h4 = reinterpret_cast<const ushort4*>(h);
  int stride = gridDim.x * 4;
  for (int i = blockIdx.x * 4 + w; i < n; i += stride) {
    ushort4 hv = h4[(size_t)i * 64 + lane];
    float fx = bf2f(hv.x), fy = bf2f(hv.y), fz = bf2f(hv.z), fw = bf2f(hv.w);
    float p = wred_sum(fx * gv.x + fy * gv.y + fz * gv.z + fw * gv.w);
    float we = __expf(p);
    ds += we;
    ax = fmaf(we, fx, ax); ay = fmaf(we, fy, ay);
    az = fmaf(we, fz, az); aw = fmaf(we, fw, aw);
  }
  red[w][lane * 4 + 0] = ax;
  red[w][lane * 4 + 1] = ay;
  red[w][lane * 4 + 2] = az;
  red[w][lane * 4 + 3] = aw;
  if (lane == 0) dred[w] = ds;
  __syncthreads();
  if (w == 0) {
#pragma unroll
    for (int c = 0; c < 4; ++c) {
      int f = lane * 4 + c;
      atomicAdd(&pool_acc[f], red[0][f] + red[1][f] + red[2][f] + red[3][f]);
    }
    if (lane == 0) atomicAdd(denom_acc, dred[0] + dred[1] + dred[2] + dred[3]);
  }
}

__global__ void pool3_kernel(const float* __restrict__ pool_acc,
                             const float* __restrict__ denom_acc,
                             float* __restrict__ out) {
  out[threadIdx.x] = pool_acc[threadIdx.x] / denom_acc[0];
}

// ---------------- launch ----------------
extern "C" void kernel_launch(void* const* d_in, const int* in_sizes, int n_in,
                              void* d_out, int out_size, void* d_ws, size_t ws_size,
                              hipStream_t stream) {
  const float* x = (const float*)d_in[0];
  const int* edge = (const int*)d_in[1];
  const float* W0 = (const float*)d_in[2];
  const float* a_src0 = (const float*)d_in[3];
  const float* a_dst0 = (const float*)d_in[4];
  const float* b0 = (const float*)d_in[5];
  const float* W1 = (const float*)d_in[6];
  const float* a_src1 = (const float*)d_in[7];
  const float* a_dst1 = (const float*)d_in[8];
  const float* b1 = (const float*)d_in[9];
  const float* gate_w = (const float*)d_in[10];
  float* out = (float*)d_out;

  char* p = (char*)d_ws;
  size_t off = 0;
  auto take = [&](size_t bytes) -> char* {
    char* r = p + off;
    off = (off + bytes + 255) & ~(size_t)255;
    return r;
  };
  u8* hA = (u8*)take((size_t)NN * 256);          // fp8 h (GEMM out, gather operand)
  u16* hB = (u16*)take((size_t)NN * 256 * 2);    // bf16 agg out
  u16* Wt0 = (u16*)take((size_t)256 * 768 * 2);
  u16* Wt1 = (u16*)take((size_t)256 * 256 * 2);
  char* zero_base = p + off;
  float* as0 = (float*)take((size_t)NN * 4);
  float* ad0 = (float*)take((size_t)NN * 4);
  float* as1 = (float*)take((size_t)NN * 4);
  float* ad1 = (float*)take((size_t)NN * 4);
  uint* bcnt = (uint*)take((size_t)NBUCK * 4);
  float* pool_acc = (float*)take(256 * 4);
  float* denom_acc = (float*)take(256);
  size_t zero_bytes = (size_t)((p + off) - zero_base);
  uint* bptr = (uint*)take((size_t)(NBUCK + 1) * 4);
  uint* bnxt = (uint*)take((size_t)NBUCK * 4);
  uint* row_ptr = (uint*)take((size_t)(NN + 1) * 4);
  uint* tmp = (uint*)take((size_t)ETOT * 4);
  uint* csr = (uint*)take((size_t)ETOT * 4);

  const int* edge_src = edge;
  const int* edge_dst = edge + EE;

  hipMemsetAsync(zero_base, 0, zero_bytes, stream);

  wt_kernel<<<(768 * 256 + 255) / 256, 256, 0, stream>>>(W0, Wt0, 768, 256);
  wt_kernel<<<(256 * 256 + 255) / 256, 256, 0, stream>>>(W1, Wt1, 256, 256);

  histb_kernel<<<256, 256, 0, stream>>>(edge_dst, bcnt);
  scanb_kernel<<<1, 1024, 0, stream>>>(bcnt, bptr, bnxt);
  bucket_scatter<<<(ETOT + ACHUNK - 1) / ACHUNK, 256, 0, stream>>>(edge_src, edge_dst, bnxt, tmp);
  bucket_sort<<<NBUCK, 256, 0, stream>>>(tmp, bptr, row_ptr, csr);

  const int ggrid = (NN + 127) / 128;
  gemm_fused<false><<<ggrid, 512, 0, stream>>>(x, Wt0, hA, a_src0, a_dst0, as0, ad0, NN, 768);
  agg_kernel<<<12500, 256, 0, stream>>>((const uint*)hA, as0, ad0, row_ptr, csr, b0, hB, NN);
  gemm_fused<true><<<ggrid, 512, 0, stream>>>(hB, Wt1, hA, a_src1, a_dst1, as1, ad1, NN, 256);
  agg_kernel<<<12500, 256, 0, stream>>>((const uint*)hA, as1, ad1, row_ptr, csr, b1, hB, NN);

  pool12_kernel<<<128, 256, 0, stream>>>(hB, gate_w, pool_acc, denom_acc, NN);
  pool3_kernel<<<1, 256, 0, stream>>>(pool_acc, denom_acc, out);
}

// Round 5
// 297.913 us; speedup vs baseline: 3.0367x; 1.0131x over previous
//
#include <hip/hip_runtime.h>

typedef unsigned int uint;
typedef unsigned short u16;
typedef unsigned char u8;

typedef __attribute__((ext_vector_type(8))) short short8;
typedef __attribute__((ext_vector_type(8))) u16 u16x8;
typedef __attribute__((ext_vector_type(4))) float f32x4;
typedef __attribute__((ext_vector_type(2))) float f32x2;

#define NN 50000
#define EE 1600000
#define ETOT (EE + NN)
#define NBUCK 782            // ceil(NN/64)
#define ACHUNK 4096
#define BCAP 8192

__device__ __forceinline__ u16 f2bf(float f) {
  uint u = __builtin_bit_cast(uint, f);
  uint r = u + 0x7fffu + ((u >> 16) & 1u);
  return (u16)(r >> 16);
}
__device__ __forceinline__ float bf2f(u16 h) {
  return __builtin_bit_cast(float, ((uint)h) << 16);
}
__device__ __forceinline__ u8 f2fp8(float f) {
  int t = __builtin_amdgcn_cvt_pk_fp8_f32(f, f, 0, false);
  return (u8)(t & 0xff);
}
__device__ __forceinline__ float wred_sum(float v) {
#pragma unroll
  for (int off = 32; off > 0; off >>= 1) v += __shfl_xor(v, off);
  return v;
}

// ---------------- tiny zero kernel: bcnt + pool_acc + denom_acc ----------------
__global__ void zero_small(uint* __restrict__ bcnt, float* __restrict__ pool_acc,
                           float* __restrict__ denom_acc) {
  int t = threadIdx.x;
  for (int i = t; i < NBUCK; i += 1024) bcnt[i] = 0u;
  if (t < 256) pool_acc[t] = 0.f;
  if (t == 0) denom_acc[0] = 0.f;
}

// ---------------- W transpose + bf16 convert: W[K][N] -> Wt[N][K] ----------------
__global__ void wt_kernel(const float* __restrict__ W, u16* __restrict__ Wt, int K, int N) {
  int i = blockIdx.x * 256 + threadIdx.x;
  if (i >= K * N) return;
  int k = i / N, n = i % N;
  Wt[(size_t)n * K + k] = f2bf(W[i]);
}

// ---------------- GEMM + fused alpha epilogue; C written as fp8 e4m3 ----------------
// as_/ad_ written directly (LDS cross-wave combine, no global atomics)
template <bool ABF16>
__global__ __launch_bounds__(512) void gemm_fused(const void* __restrict__ Avoid,
                                                  const u16* __restrict__ Bt,
                                                  u8* __restrict__ C8,
                                                  const float* __restrict__ a_src,
                                                  const float* __restrict__ a_dst,
                                                  float* __restrict__ as_,
                                                  float* __restrict__ ad_,
                                                  int M, int K) {
  __shared__ __align__(16) u16 As[128 * 64];
  __shared__ __align__(16) u16 Bs[256 * 64];
  __shared__ float asLds[4][128];
  __shared__ float adLds[4][128];
  const int m0 = blockIdx.x * 128;
  const int tid = threadIdx.x;
  const int lane = tid & 63;
  const int wv = tid >> 6;
  const int wm = wv >> 2, wn = wv & 3;

  f32x4 acc[4][4] = {};

  const int sr = tid >> 2;
  const int skc = (tid & 3) * 16;
  const int br = tid >> 1;
  const int bk = (tid & 1) * 32;

  for (int k0 = 0; k0 < K; k0 += 64) {
    {
      int grow = m0 + sr;
      if constexpr (!ABF16) {
        const float* A = (const float*)Avoid;
        float4 f[4];
        if (grow < M) {
          const float4* src = reinterpret_cast<const float4*>(A + (size_t)grow * K + k0 + skc);
#pragma unroll
          for (int i = 0; i < 4; ++i) f[i] = src[i];
        } else {
#pragma unroll
          for (int i = 0; i < 4; ++i) f[i] = make_float4(0.f, 0.f, 0.f, 0.f);
        }
#pragma unroll
        for (int i = 0; i < 2; ++i) {
          u16x8 v;
          v[0] = f2bf(f[2 * i].x); v[1] = f2bf(f[2 * i].y);
          v[2] = f2bf(f[2 * i].z); v[3] = f2bf(f[2 * i].w);
          v[4] = f2bf(f[2 * i + 1].x); v[5] = f2bf(f[2 * i + 1].y);
          v[6] = f2bf(f[2 * i + 1].z); v[7] = f2bf(f[2 * i + 1].w);
          int k = skc + i * 8;
          int idx = (sr << 6) + (k ^ ((sr & 7) << 3));
          *reinterpret_cast<u16x8*>(&As[idx]) = v;
        }
      } else {
        const u16* A = (const u16*)Avoid;
        u16x8 v[2];
        if (grow < M) {
          const u16x8* src = reinterpret_cast<const u16x8*>(A + (size_t)grow * K + k0 + skc);
          v[0] = src[0]; v[1] = src[1];
        } else {
          v[0] = (u16x8)0; v[1] = (u16x8)0;
        }
#pragma unroll
        for (int i = 0; i < 2; ++i) {
          int k = skc + i * 8;
          int idx = (sr << 6) + (k ^ ((sr & 7) << 3));
          *reinterpret_cast<u16x8*>(&As[idx]) = v[i];
        }
      }
    }
    {
      const u16x8* src = reinterpret_cast<const u16x8*>(Bt + (size_t)br * K + k0 + bk);
#pragma unroll
      for (int i = 0; i < 4; ++i) {
        u16x8 v = src[i];
        int k = bk + i * 8;
        int idx = (br << 6) + (k ^ ((br & 7) << 3));
        *reinterpret_cast<u16x8*>(&Bs[idx]) = v;
      }
    }
    __syncthreads();
#pragma unroll
    for (int kk = 0; kk < 2; ++kk) {
      short8 af[4], bfr[4];
      const int kb = kk * 32 + (lane >> 4) * 8;
#pragma unroll
      for (int m = 0; m < 4; ++m) {
        int r = wm * 64 + m * 16 + (lane & 15);
        int idx = (r << 6) + (kb ^ ((r & 7) << 3));
        af[m] = *reinterpret_cast<const short8*>(&As[idx]);
      }
#pragma unroll
      for (int n = 0; n < 4; ++n) {
        int c = wn * 64 + n * 16 + (lane & 15);
        int idx = (c << 6) + (kb ^ ((c & 7) << 3));
        bfr[n] = *reinterpret_cast<const short8*>(&Bs[idx]);
      }
#pragma unroll
      for (int m = 0; m < 4; ++m)
#pragma unroll
        for (int n = 0; n < 4; ++n)
          acc[m][n] = __builtin_amdgcn_mfma_f32_16x16x32_bf16(af[m], bfr[n], acc[m][n], 0, 0, 0);
    }
    __syncthreads();
  }

  const int g = lane >> 4;
  const int cl = lane & 15;
  float asv[4], adv[4];
#pragma unroll
  for (int n = 0; n < 4; ++n) {
    int c = wn * 64 + n * 16 + cl;
    asv[n] = a_src[c];
    adv[n] = a_dst[c];
  }
#pragma unroll
  for (int m = 0; m < 4; ++m) {
#pragma unroll
    for (int reg = 0; reg < 4; ++reg) {
      int rl = wm * 64 + m * 16 + g * 4 + reg;   // local row 0..127
      int row = m0 + rl;
      float ps = 0.f, pd = 0.f;
      if (row < M) {
#pragma unroll
        for (int n = 0; n < 4; ++n) {
          float v = acc[m][n][reg];
          C8[(size_t)row * 256 + wn * 64 + n * 16 + cl] = f2fp8(v);
          ps = fmaf(v, asv[n], ps);
          pd = fmaf(v, adv[n], pd);
        }
      }
#pragma unroll
      for (int off = 1; off < 16; off <<= 1) {
        ps += __shfl_xor(ps, off);
        pd += __shfl_xor(pd, off);
      }
      if (cl == 0) {
        asLds[wn][rl] = ps;
        adLds[wn][rl] = pd;
      }
    }
  }
  __syncthreads();
  if (tid < 128) {
    int row = m0 + tid;
    if (row < M) {
      as_[row] = asLds[0][tid] + asLds[1][tid] + asLds[2][tid] + asLds[3][tid];
      ad_[row] = adLds[0][tid] + adLds[1][tid] + adLds[2][tid] + adLds[3][tid];
    }
  }
}

// ---------------- CSR build: two-level counting sort ----------------
__global__ __launch_bounds__(256) void histb_kernel(const int* __restrict__ edge_dst,
                                                    uint* __restrict__ bcnt) {
  __shared__ uint h[NBUCK];
  for (int i = threadIdx.x; i < NBUCK; i += 256) h[i] = 0;
  __syncthreads();
  int stride = gridDim.x * 256;
  for (int i = blockIdx.x * 256 + threadIdx.x; i < EE / 4; i += stride) {
    int4 d = reinterpret_cast<const int4*>(edge_dst)[i];
    atomicAdd(&h[d.x >> 6], 1u);
    atomicAdd(&h[d.y >> 6], 1u);
    atomicAdd(&h[d.z >> 6], 1u);
    atomicAdd(&h[d.w >> 6], 1u);
  }
  __syncthreads();
  for (int i = threadIdx.x; i < NBUCK; i += 256) {
    uint v = h[i];
    if (v) atomicAdd(&bcnt[i], v);
  }
}

__global__ __launch_bounds__(1024) void scanb_kernel(const uint* __restrict__ bcnt,
                                                     uint* __restrict__ bptr,
                                                     uint* __restrict__ bnxt) {
  __shared__ uint wsum[16];
  int tid = threadIdx.x, lane = tid & 63, w = tid >> 6;
  uint v = 0;
  if (tid < NBUCK) {
    int self = NN - tid * 64;
    if (self > 64) self = 64;
    v = bcnt[tid] + (uint)self;
  }
  uint x = v;
#pragma unroll
  for (int off = 1; off < 64; off <<= 1) {
    uint t = __shfl_up(x, off);
    if (lane >= off) x += t;
  }
  if (lane == 63) wsum[w] = x;
  __syncthreads();
  uint woff = 0;
  for (int k = 0; k < w; ++k) woff += wsum[k];
  uint excl = woff + x - v;
  if (tid < NBUCK) { bptr[tid] = excl; bnxt[tid] = excl; }
  if (tid == NBUCK) bptr[NBUCK] = excl;
}

__global__ __launch_bounds__(256) void bucket_scatter(const int* __restrict__ esrc,
                                                      const int* __restrict__ edst,
                                                      uint* __restrict__ bnxt,
                                                      uint* __restrict__ tmp) {
  __shared__ uint lh[NBUCK];
  int base = blockIdx.x * ACHUNK;
  int nE = ETOT - base; if (nE > ACHUNK) nE = ACHUNK;
  for (int i = threadIdx.x; i < NBUCK; i += 256) lh[i] = 0;
  __syncthreads();
  for (int k = threadIdx.x; k < nE; k += 256) {
    int e = base + k;
    int d = (e < EE) ? edst[e] : (e - EE);
    atomicAdd(&lh[d >> 6], 1u);
  }
  __syncthreads();
  for (int i = threadIdx.x; i < NBUCK; i += 256) {
    uint c = lh[i];
    lh[i] = c ? atomicAdd(&bnxt[i], c) : 0u;
  }
  __syncthreads();
  for (int k = threadIdx.x; k < nE; k += 256) {
    int e = base + k;
    int s, d;
    if (e < EE) { s = esrc[e]; d = edst[e]; } else { s = e - EE; d = s; }
    uint pos = atomicAdd(&lh[d >> 6], 1u);
    tmp[pos] = ((uint)(d & 63) << 16) | (uint)s;
  }
}

__global__ __launch_bounds__(256) void bucket_sort(const uint* __restrict__ tmp,
                                                   const uint* __restrict__ bptr,
                                                   uint* __restrict__ row_ptr,
                                                   uint* __restrict__ csr) {
  __shared__ uint lh[64];
  __shared__ uint buf[BCAP];
  int b = blockIdx.x;
  uint s0 = bptr[b], s1 = bptr[b + 1];
  int cnt = (int)(s1 - s0);
  int tid = threadIdx.x;
  if (tid < 64) lh[tid] = 0;
  __syncthreads();
  for (int i = tid; i < cnt; i += 256) {
    uint v = tmp[s0 + i];
    buf[i] = v;
    atomicAdd(&lh[v >> 16], 1u);
  }
  __syncthreads();
  if (tid < 64) {
    uint v = lh[tid];
    uint x = v;
#pragma unroll
    for (int off = 1; off < 64; off <<= 1) {
      uint t = __shfl_up(x, off);
      if (tid >= off) x += t;
    }
    uint pos = s0 + x - v;
    int d = b * 64 + tid;
    if (d < NN) row_ptr[d] = pos;
    lh[tid] = pos;
    if (b == NBUCK - 1 && tid == 0) row_ptr[NN] = s1;
  }
  __syncthreads();
  for (int i = tid; i < cnt; i += 256) {
    uint v = buf[i];
    uint pos = atomicAdd(&lh[v >> 16], 1u);
    csr[pos] = v & 0xFFFFu;
  }
}

// ---------------- GAT aggregation (fp8 gather): out=relu(msg/denom + b), bf16 ----------------
__global__ __launch_bounds__(256) void agg_kernel(const uint* __restrict__ h8,
                                                  const float* __restrict__ as_,
                                                  const float* __restrict__ ad_,
                                                  const uint* __restrict__ row_ptr,
                                                  const uint* __restrict__ csr_src,
                                                  const float* __restrict__ bias,
                                                  u16* __restrict__ out, int n) {
  int wid = (blockIdx.x * 256 + threadIdx.x) >> 6;
  int lane = threadIdx.x & 63;
  if (wid >= n) return;
  uint start = row_ptr[wid], end = row_ptr[wid + 1];
  float adi = ad_[wid];
  float ax = 0.f, ay = 0.f, az = 0.f, aw = 0.f;
  float denom = 0.f;
  for (uint base = start; base < end; base += 64) {
    int cnt = (int)(end - base);
    if (cnt > 64) cnt = 64;
    float w = 0.f;
    int s = 0;
    if (lane < cnt) {
      s = (int)csr_src[base + lane];
      float e = as_[s] + adi;
      e = e > 0.f ? e : 0.2f * e;
      w = __expf(e);
    }
    denom += w;
    int j = 0;
    for (; j + 8 <= cnt; j += 8) {
      uint v[8];
      float ww[8];
#pragma unroll
      for (int q = 0; q < 8; ++q) {
        int sq = __shfl(s, j + q);
        ww[q] = __shfl(w, j + q);
        v[q] = h8[(size_t)sq * 64 + lane];
      }
#pragma unroll
      for (int q = 0; q < 8; ++q) {
        f32x2 lo = __builtin_amdgcn_cvt_pk_f32_fp8(v[q], false);
        f32x2 hi = __builtin_amdgcn_cvt_pk_f32_fp8(v[q], true);
        ax = fmaf(ww[q], lo.x, ax); ay = fmaf(ww[q], lo.y, ay);
        az = fmaf(ww[q], hi.x, az); aw = fmaf(ww[q], hi.y, aw);
      }
    }
    for (; j < cnt; ++j) {
      int sj = __shfl(s, j);
      float wj = __shfl(w, j);
      uint v = h8[(size_t)sj * 64 + lane];
      f32x2 lo = __builtin_amdgcn_cvt_pk_f32_fp8(v, false);
      f32x2 hi = __builtin_amdgcn_cvt_pk_f32_fp8(v, true);
      ax = fmaf(wj, lo.x, ax); ay = fmaf(wj, lo.y, ay);
      az = fmaf(wj, hi.x, az); aw = fmaf(wj, hi.y, aw);
    }
  }
  denom = wred_sum(denom);
  float inv = 1.f / (denom + 1e-16f);
  float4 b = reinterpret_cast<const float4*>(bias)[lane];
  ushort4 o;
  o.x = f2bf(fmaxf(fmaf(ax, inv, b.x), 0.f));
  o.y = f2bf(fmaxf(fmaf(ay, inv, b.y), 0.f));
  o.z = f2bf(fmaxf(fmaf(az, inv, b.z), 0.f));
  o.w = f2bf(fmaxf(fmaf(aw, inv, b.w), 0.f));
  reinterpret_cast<ushort4*>(out)[(size_t)wid * 64 + lane] = o;
}

// ---------------- fused global-attention pooling (unnormalized) ----------------
__global__ __launch_bounds__(256) void pool12_kernel(const u16* __restrict__ h,
                                                     const float* __restrict__ gate_w,
                                                     float* __restrict__ pool_acc,
                                                     float* __restrict__ denom_acc, int n) {
  __shared__ float red[4][256];
  __shared__ float dred[4];
  int lane = threadIdx.x & 63, w = threadIdx.x >> 6;
  float ax = 0.f, ay = 0.f, az = 0.f, aw = 0.f, ds = 0.f;
  float4 gv = reinterpret_cast<const float4*>(gate_w)[lane];
  const ushort4* __restrict__ h4 = reinterpret_cast<const ushort4*>(h);
  int stride = gridDim.x * 4;
  for (int i = blockIdx.x * 4 + w; i < n; i += stride) {
    ushort4 hv = h4[(size_t)i * 64 + lane];
    float fx = bf2f(hv.x), fy = bf2f(hv.y), fz = bf2f(hv.z), fw = bf2f(hv.w);
    float p = wred_sum(fx * gv.x + fy * gv.y + fz * gv.z + fw * gv.w);
    float we = __expf(p);
    ds += we;
    ax = fmaf(we, fx, ax); ay = fmaf(we, fy, ay);
    az = fmaf(we, fz, az); aw = fmaf(we, fw, aw);
  }
  red[w][lane * 4 + 0] = ax;
  red[w][lane * 4 + 1] = ay;
  red[w][lane * 4 + 2] = az;
  red[w][lane * 4 + 3] = aw;
  if (lane == 0) dred[w] = ds;
  __syncthreads();
  if (w == 0) {
#pragma unroll
    for (int c = 0; c < 4; ++c) {
      int f = lane * 4 + c;
      atomicAdd(&pool_acc[f], red[0][f] + red[1][f] + red[2][f] + red[3][f]);
    }
    if (lane == 0) atomicAdd(denom_acc, dred[0] + dred[1] + dred[2] + dred[3]);
  }
}

__global__ void pool3_kernel(const float* __restrict__ pool_acc,
                             const float* __restrict__ denom_acc,
                             float* __restrict__ out) {
  out[threadIdx.x] = pool_acc[threadIdx.x] / denom_acc[0];
}

// ---------------- launch ----------------
extern "C" void kernel_launch(void* const* d_in, const int* in_sizes, int n_in,
                              void* d_out, int out_size, void* d_ws, size_t ws_size,
                              hipStream_t stream) {
  const float* x = (const float*)d_in[0];
  const int* edge = (const int*)d_in[1];
  const float* W0 = (const float*)d_in[2];
  const float* a_src0 = (const float*)d_in[3];
  const float* a_dst0 = (const float*)d_in[4];
  const float* b0 = (const float*)d_in[5];
  const float* W1 = (const float*)d_in[6];
  const float* a_src1 = (const float*)d_in[7];
  const float* a_dst1 = (const float*)d_in[8];
  const float* b1 = (const float*)d_in[9];
  const float* gate_w = (const float*)d_in[10];
  float* out = (float*)d_out;

  char* p = (char*)d_ws;
  size_t off = 0;
  auto take = [&](size_t bytes) -> char* {
    char* r = p + off;
    off = (off + bytes + 255) & ~(size_t)255;
    return r;
  };
  u8* hA = (u8*)take((size_t)NN * 256);          // fp8 h (GEMM out, gather operand)
  u16* hB = (u16*)take((size_t)NN * 256 * 2);    // bf16 agg out
  u16* Wt0 = (u16*)take((size_t)256 * 768 * 2);
  u16* Wt1 = (u16*)take((size_t)256 * 256 * 2);
  float* as0 = (float*)take((size_t)NN * 4);
  float* ad0 = (float*)take((size_t)NN * 4);
  float* as1 = (float*)take((size_t)NN * 4);
  float* ad1 = (float*)take((size_t)NN * 4);
  uint* bcnt = (uint*)take((size_t)NBUCK * 4);
  float* pool_acc = (float*)take(256 * 4);
  float* denom_acc = (float*)take(256);
  uint* bptr = (uint*)take((size_t)(NBUCK + 1) * 4);
  uint* bnxt = (uint*)take((size_t)NBUCK * 4);
  uint* row_ptr = (uint*)take((size_t)(NN + 1) * 4);
  uint* tmp = (uint*)take((size_t)ETOT * 4);
  uint* csr = (uint*)take((size_t)ETOT * 4);

  const int* edge_src = edge;
  const int* edge_dst = edge + EE;

  zero_small<<<1, 1024, 0, stream>>>(bcnt, pool_acc, denom_acc);

  wt_kernel<<<(768 * 256 + 255) / 256, 256, 0, stream>>>(W0, Wt0, 768, 256);
  wt_kernel<<<(256 * 256 + 255) / 256, 256, 0, stream>>>(W1, Wt1, 256, 256);

  histb_kernel<<<256, 256, 0, stream>>>(edge_dst, bcnt);
  scanb_kernel<<<1, 1024, 0, stream>>>(bcnt, bptr, bnxt);
  bucket_scatter<<<(ETOT + ACHUNK - 1) / ACHUNK, 256, 0, stream>>>(edge_src, edge_dst, bnxt, tmp);
  bucket_sort<<<NBUCK, 256, 0, stream>>>(tmp, bptr, row_ptr, csr);

  const int ggrid = (NN + 127) / 128;
  gemm_fused<false><<<ggrid, 512, 0, stream>>>(x, Wt0, hA, a_src0, a_dst0, as0, ad0, NN, 768);
  agg_kernel<<<12500, 256, 0, stream>>>((const uint*)hA, as0, ad0, row_ptr, csr, b0, hB, NN);
  gemm_fused<true><<<ggrid, 512, 0, stream>>>(hB, Wt1, hA, a_src1, a_dst1, as1, ad1, NN, 256);
  agg_kernel<<<12500, 256, 0, stream>>>((const uint*)hA, as1, ad1, row_ptr, csr, b1, hB, NN);

  pool12_kernel<<<128, 256, 0, stream>>>(hB, gate_w, pool_acc, denom_acc, NN);
  pool3_kernel<<<1, 256, 0, stream>>>(pool_acc, denom_acc, out);
}

// Round 6
// 293.130 us; speedup vs baseline: 3.0862x; 1.0163x over previous
//
#include <hip/hip_runtime.h>

typedef unsigned int uint;
typedef unsigned short u16;
typedef unsigned char u8;

typedef __attribute__((ext_vector_type(8))) short short8;
typedef __attribute__((ext_vector_type(8))) u16 u16x8;
typedef __attribute__((ext_vector_type(4))) float f32x4;
typedef __attribute__((ext_vector_type(2))) float f32x2;

#define NN 50000
#define EE 1600000
#define ETOT (EE + NN)
#define NBUCK 782            // ceil(NN/64)
#define ACHUNK 8192
#define CAP 2432             // per-bucket capacity (mean 2112, +7 sigma)
#define NSLOT 64
#define SLOTW 260            // 256 cols + denom @256, padded

__device__ __forceinline__ u16 f2bf(float f) {
  uint u = __builtin_bit_cast(uint, f);
  uint r = u + 0x7fffu + ((u >> 16) & 1u);
  return (u16)(r >> 16);
}
__device__ __forceinline__ float bf2f(u16 h) {
  return __builtin_bit_cast(float, ((uint)h) << 16);
}
__device__ __forceinline__ u8 f2fp8(float f) {
  int t = __builtin_amdgcn_cvt_pk_fp8_f32(f, f, 0, false);
  return (u8)(t & 0xff);
}
__device__ __forceinline__ float wred_sum(float v) {
#pragma unroll
  for (int off = 32; off > 0; off >>= 1) v += __shfl_xor(v, off);
  return v;
}

// ---------------- zero: bnxt + pool slots ----------------
__global__ void zero_ws(uint* __restrict__ bnxt, float* __restrict__ slots) {
  int i = blockIdx.x * 256 + threadIdx.x;
  if (i < NBUCK) bnxt[i] = 0u;
  if (i < NSLOT * SLOTW) slots[i] = 0.f;
}

// ---------------- W0+W1 transpose + bf16 convert ----------------
__global__ void wt_both(const float* __restrict__ W0, const float* __restrict__ W1,
                        u16* __restrict__ Wt0, u16* __restrict__ Wt1) {
  int i = blockIdx.x * 256 + threadIdx.x;
  if (i < 768 * 256) {
    int k = i >> 8, n = i & 255;
    Wt0[n * 768 + k] = f2bf(W0[i]);
  } else if (i < 768 * 256 + 256 * 256) {
    int j = i - 768 * 256;
    int k = j >> 8, n = j & 255;
    Wt1[n * 256 + k] = f2bf(W1[j]);
  }
}

// ---------------- GEMM + fused alpha epilogue; C written as fp8 e4m3 ----------------
template <bool ABF16>
__global__ __launch_bounds__(512) void gemm_fused(const void* __restrict__ Avoid,
                                                  const u16* __restrict__ Bt,
                                                  u8* __restrict__ C8,
                                                  const float* __restrict__ a_src,
                                                  const float* __restrict__ a_dst,
                                                  float* __restrict__ as_,
                                                  float* __restrict__ ad_,
                                                  int M, int K) {
  __shared__ __align__(16) u16 As[128 * 64];
  __shared__ __align__(16) u16 Bs[256 * 64];
  __shared__ float asLds[4][128];
  __shared__ float adLds[4][128];
  const int m0 = blockIdx.x * 128;
  const int tid = threadIdx.x;
  const int lane = tid & 63;
  const int wv = tid >> 6;
  const int wm = wv >> 2, wn = wv & 3;

  f32x4 acc[4][4] = {};

  const int sr = tid >> 2;
  const int skc = (tid & 3) * 16;
  const int br = tid >> 1;
  const int bk = (tid & 1) * 32;

  for (int k0 = 0; k0 < K; k0 += 64) {
    {
      int grow = m0 + sr;
      if constexpr (!ABF16) {
        const float* A = (const float*)Avoid;
        float4 f[4];
        if (grow < M) {
          const float4* src = reinterpret_cast<const float4*>(A + (size_t)grow * K + k0 + skc);
#pragma unroll
          for (int i = 0; i < 4; ++i) f[i] = src[i];
        } else {
#pragma unroll
          for (int i = 0; i < 4; ++i) f[i] = make_float4(0.f, 0.f, 0.f, 0.f);
        }
#pragma unroll
        for (int i = 0; i < 2; ++i) {
          u16x8 v;
          v[0] = f2bf(f[2 * i].x); v[1] = f2bf(f[2 * i].y);
          v[2] = f2bf(f[2 * i].z); v[3] = f2bf(f[2 * i].w);
          v[4] = f2bf(f[2 * i + 1].x); v[5] = f2bf(f[2 * i + 1].y);
          v[6] = f2bf(f[2 * i + 1].z); v[7] = f2bf(f[2 * i + 1].w);
          int k = skc + i * 8;
          int idx = (sr << 6) + (k ^ ((sr & 7) << 3));
          *reinterpret_cast<u16x8*>(&As[idx]) = v;
        }
      } else {
        const u16* A = (const u16*)Avoid;
        u16x8 v[2];
        if (grow < M) {
          const u16x8* src = reinterpret_cast<const u16x8*>(A + (size_t)grow * K + k0 + skc);
          v[0] = src[0]; v[1] = src[1];
        } else {
          v[0] = (u16x8)0; v[1] = (u16x8)0;
        }
#pragma unroll
        for (int i = 0; i < 2; ++i) {
          int k = skc + i * 8;
          int idx = (sr << 6) + (k ^ ((sr & 7) << 3));
          *reinterpret_cast<u16x8*>(&As[idx]) = v[i];
        }
      }
    }
    {
      const u16x8* src = reinterpret_cast<const u16x8*>(Bt + (size_t)br * K + k0 + bk);
#pragma unroll
      for (int i = 0; i < 4; ++i) {
        u16x8 v = src[i];
        int k = bk + i * 8;
        int idx = (br << 6) + (k ^ ((br & 7) << 3));
        *reinterpret_cast<u16x8*>(&Bs[idx]) = v;
      }
    }
    __syncthreads();
#pragma unroll
    for (int kk = 0; kk < 2; ++kk) {
      short8 af[4], bfr[4];
      const int kb = kk * 32 + (lane >> 4) * 8;
#pragma unroll
      for (int m = 0; m < 4; ++m) {
        int r = wm * 64 + m * 16 + (lane & 15);
        int idx = (r << 6) + (kb ^ ((r & 7) << 3));
        af[m] = *reinterpret_cast<const short8*>(&As[idx]);
      }
#pragma unroll
      for (int n = 0; n < 4; ++n) {
        int c = wn * 64 + n * 16 + (lane & 15);
        int idx = (c << 6) + (kb ^ ((c & 7) << 3));
        bfr[n] = *reinterpret_cast<const short8*>(&Bs[idx]);
      }
#pragma unroll
      for (int m = 0; m < 4; ++m)
#pragma unroll
        for (int n = 0; n < 4; ++n)
          acc[m][n] = __builtin_amdgcn_mfma_f32_16x16x32_bf16(af[m], bfr[n], acc[m][n], 0, 0, 0);
    }
    __syncthreads();
  }

  const int g = lane >> 4;
  const int cl = lane & 15;
  float asv[4], adv[4];
#pragma unroll
  for (int n = 0; n < 4; ++n) {
    int c = wn * 64 + n * 16 + cl;
    asv[n] = a_src[c];
    adv[n] = a_dst[c];
  }
#pragma unroll
  for (int m = 0; m < 4; ++m) {
#pragma unroll
    for (int reg = 0; reg < 4; ++reg) {
      int rl = wm * 64 + m * 16 + g * 4 + reg;
      int row = m0 + rl;
      float ps = 0.f, pd = 0.f;
      if (row < M) {
#pragma unroll
        for (int n = 0; n < 4; ++n) {
          float v = acc[m][n][reg];
          C8[(size_t)row * 256 + wn * 64 + n * 16 + cl] = f2fp8(v);
          ps = fmaf(v, asv[n], ps);
          pd = fmaf(v, adv[n], pd);
        }
      }
#pragma unroll
      for (int off = 1; off < 16; off <<= 1) {
        ps += __shfl_xor(ps, off);
        pd += __shfl_xor(pd, off);
      }
      if (cl == 0) {
        asLds[wn][rl] = ps;
        adLds[wn][rl] = pd;
      }
    }
  }
  __syncthreads();
  if (tid < 128) {
    int row = m0 + tid;
    if (row < M) {
      as_[row] = asLds[0][tid] + asLds[1][tid] + asLds[2][tid] + asLds[3][tid];
      ad_[row] = adLds[0][tid] + adLds[1][tid] + adLds[2][tid] + adLds[3][tid];
    }
  }
}

// ---------------- CSR build: fixed-capacity bucket scatter (no pre-histogram) ----------------
__global__ __launch_bounds__(256) void bucket_scatter(const int* __restrict__ esrc,
                                                      const int* __restrict__ edst,
                                                      uint* __restrict__ bnxt,
                                                      uint* __restrict__ tmp) {
  __shared__ uint lh[NBUCK];
  int base = blockIdx.x * ACHUNK;
  int nE = ETOT - base; if (nE > ACHUNK) nE = ACHUNK;
  for (int i = threadIdx.x; i < NBUCK; i += 256) lh[i] = 0;
  __syncthreads();
  for (int k = threadIdx.x; k < nE; k += 256) {
    int e = base + k;
    int d = (e < EE) ? edst[e] : (e - EE);
    atomicAdd(&lh[d >> 6], 1u);
  }
  __syncthreads();
  for (int i = threadIdx.x; i < NBUCK; i += 256) {
    uint c = lh[i];
    lh[i] = c ? atomicAdd(&bnxt[i], c) : 0u;
  }
  __syncthreads();
  for (int k = threadIdx.x; k < nE; k += 256) {
    int e = base + k;
    int s, d;
    if (e < EE) { s = esrc[e]; d = edst[e]; } else { s = e - EE; d = s; }
    uint pos = atomicAdd(&lh[d >> 6], 1u);
    tmp[(size_t)(d >> 6) * CAP + pos] = ((uint)(d & 63) << 16) | (uint)s;
  }
}

// exclusive scan of bucket counts (bnxt, post-scatter) -> bptr
__global__ __launch_bounds__(1024) void scanb_kernel(const uint* __restrict__ bnxt,
                                                     uint* __restrict__ bptr) {
  __shared__ uint wsum[16];
  int tid = threadIdx.x, lane = tid & 63, w = tid >> 6;
  uint v = (tid < NBUCK) ? bnxt[tid] : 0u;
  uint x = v;
#pragma unroll
  for (int off = 1; off < 64; off <<= 1) {
    uint t = __shfl_up(x, off);
    if (lane >= off) x += t;
  }
  if (lane == 63) wsum[w] = x;
  __syncthreads();
  uint woff = 0;
  for (int k = 0; k < w; ++k) woff += wsum[k];
  uint excl = woff + x - v;
  if (tid < NBUCK) bptr[tid] = excl;
}

// per-bucket 64-bin counting sort -> final csr (u16) + row_ptr
__global__ __launch_bounds__(256) void bucket_sort(const uint* __restrict__ tmp,
                                                   const uint* __restrict__ bptr,
                                                   const uint* __restrict__ bnxt,
                                                   uint* __restrict__ row_ptr,
                                                   u16* __restrict__ csr) {
  __shared__ uint lh[64];
  __shared__ uint buf[CAP];
  int b = blockIdx.x;
  uint s0 = bptr[b];
  int cnt = (int)bnxt[b];
  int tid = threadIdx.x;
  if (tid < 64) lh[tid] = 0;
  __syncthreads();
  for (int i = tid; i < cnt; i += 256) {
    uint v = tmp[(size_t)b * CAP + i];
    buf[i] = v;
    atomicAdd(&lh[v >> 16], 1u);
  }
  __syncthreads();
  if (tid < 64) {
    uint v = lh[tid];
    uint x = v;
#pragma unroll
    for (int off = 1; off < 64; off <<= 1) {
      uint t = __shfl_up(x, off);
      if (tid >= off) x += t;
    }
    uint pos = s0 + x - v;
    int d = b * 64 + tid;
    if (d < NN) row_ptr[d] = pos;
    lh[tid] = pos;
    if (b == NBUCK - 1 && tid == 0) row_ptr[NN] = s0 + (uint)cnt;
  }
  __syncthreads();
  for (int i = tid; i < cnt; i += 256) {
    uint v = buf[i];
    uint pos = atomicAdd(&lh[v >> 16], 1u);
    csr[pos] = (u16)(v & 0xFFFFu);
  }
}

// ---------------- GAT aggregation (fp8 gather); POOL fuses global attention ----------------
template <bool POOL>
__global__ __launch_bounds__(256) void agg_kernel(const uint* __restrict__ h8,
                                                  const float* __restrict__ as_,
                                                  const float* __restrict__ ad_,
                                                  const uint* __restrict__ row_ptr,
                                                  const u16* __restrict__ csr_src,
                                                  const float* __restrict__ bias,
                                                  u16* __restrict__ out,
                                                  const float* __restrict__ gate_w,
                                                  float* __restrict__ slots, int n) {
  __shared__ float lp[257];
  int wid = (blockIdx.x * 256 + threadIdx.x) >> 6;
  int lane = threadIdx.x & 63;
  if (POOL) {
    for (int i = threadIdx.x; i < 257; i += 256) lp[i] = 0.f;
    __syncthreads();
  }
  if (wid < n) {
    uint start = row_ptr[wid], end = row_ptr[wid + 1];
    float adi = ad_[wid];
    float ax = 0.f, ay = 0.f, az = 0.f, aw = 0.f;
    float denom = 0.f;
    for (uint base = start; base < end; base += 64) {
      int cnt = (int)(end - base);
      if (cnt > 64) cnt = 64;
      float w = 0.f;
      int s = 0;
      if (lane < cnt) {
        s = (int)csr_src[base + lane];
        float e = as_[s] + adi;
        e = e > 0.f ? e : 0.2f * e;
        w = __expf(e);
      }
      denom += w;
      int j = 0;
      for (; j + 8 <= cnt; j += 8) {
        uint v[8];
        float ww[8];
#pragma unroll
        for (int q = 0; q < 8; ++q) {
          int sq = __shfl(s, j + q);
          ww[q] = __shfl(w, j + q);
          v[q] = h8[(size_t)sq * 64 + lane];
        }
#pragma unroll
        for (int q = 0; q < 8; ++q) {
          f32x2 lo = __builtin_amdgcn_cvt_pk_f32_fp8(v[q], false);
          f32x2 hi = __builtin_amdgcn_cvt_pk_f32_fp8(v[q], true);
          ax = fmaf(ww[q], lo.x, ax); ay = fmaf(ww[q], lo.y, ay);
          az = fmaf(ww[q], hi.x, az); aw = fmaf(ww[q], hi.y, aw);
        }
      }
      for (; j < cnt; ++j) {
        int sj = __shfl(s, j);
        float wj = __shfl(w, j);
        uint v = h8[(size_t)sj * 64 + lane];
        f32x2 lo = __builtin_amdgcn_cvt_pk_f32_fp8(v, false);
        f32x2 hi = __builtin_amdgcn_cvt_pk_f32_fp8(v, true);
        ax = fmaf(wj, lo.x, ax); ay = fmaf(wj, lo.y, ay);
        az = fmaf(wj, hi.x, az); aw = fmaf(wj, hi.y, aw);
      }
    }
    denom = wred_sum(denom);
    float inv = 1.f / (denom + 1e-16f);
    float4 b = reinterpret_cast<const float4*>(bias)[lane];
    float ox = fmaxf(fmaf(ax, inv, b.x), 0.f);
    float oy = fmaxf(fmaf(ay, inv, b.y), 0.f);
    float oz = fmaxf(fmaf(az, inv, b.z), 0.f);
    float ow = fmaxf(fmaf(aw, inv, b.w), 0.f);
    if (!POOL) {
      ushort4 o;
      o.x = f2bf(ox); o.y = f2bf(oy); o.z = f2bf(oz); o.w = f2bf(ow);
      reinterpret_cast<ushort4*>(out)[(size_t)wid * 64 + lane] = o;
    } else {
      float4 gv = reinterpret_cast<const float4*>(gate_w)[lane];
      float pg = wred_sum(ox * gv.x + oy * gv.y + oz * gv.z + ow * gv.w);
      float we = __expf(pg);
      int c0 = lane * 4;
      atomicAdd(&lp[c0 + 0], we * ox);
      atomicAdd(&lp[c0 + 1], we * oy);
      atomicAdd(&lp[c0 + 2], we * oz);
      atomicAdd(&lp[c0 + 3], we * ow);
      if (lane == 0) atomicAdd(&lp[256], we);
    }
  }
  if (POOL) {
    __syncthreads();
    int slot = blockIdx.x & (NSLOT - 1);
    for (int i = threadIdx.x; i < 257; i += 256) {
      float v = lp[i];
      if (v != 0.f) atomicAdd(&slots[slot * SLOTW + i], v);
    }
  }
}

// ---------------- final: reduce slots, normalize ----------------
__global__ void pool3_kernel(const float* __restrict__ slots, float* __restrict__ out) {
  __shared__ float dsh;
  int tid = threadIdx.x;
  float acc = 0.f;
  for (int s = 0; s < NSLOT; ++s) acc += slots[s * SLOTW + tid];
  if (tid == 0) {
    float d = 0.f;
    for (int s = 0; s < NSLOT; ++s) d += slots[s * SLOTW + 256];
    dsh = d;
  }
  __syncthreads();
  out[tid] = acc / dsh;
}

// ---------------- launch ----------------
extern "C" void kernel_launch(void* const* d_in, const int* in_sizes, int n_in,
                              void* d_out, int out_size, void* d_ws, size_t ws_size,
                              hipStream_t stream) {
  const float* x = (const float*)d_in[0];
  const int* edge = (const int*)d_in[1];
  const float* W0 = (const float*)d_in[2];
  const float* a_src0 = (const float*)d_in[3];
  const float* a_dst0 = (const float*)d_in[4];
  const float* b0 = (const float*)d_in[5];
  const float* W1 = (const float*)d_in[6];
  const float* a_src1 = (const float*)d_in[7];
  const float* a_dst1 = (const float*)d_in[8];
  const float* b1 = (const float*)d_in[9];
  const float* gate_w = (const float*)d_in[10];
  float* out = (float*)d_out;

  char* p = (char*)d_ws;
  size_t off = 0;
  auto take = [&](size_t bytes) -> char* {
    char* r = p + off;
    off = (off + bytes + 255) & ~(size_t)255;
    return r;
  };
  u8* hA = (u8*)take((size_t)NN * 256);          // fp8 h (GEMM out, gather operand)
  u16* hB = (u16*)take((size_t)NN * 256 * 2);    // bf16 agg0 out (gemm1 input)
  u16* Wt0 = (u16*)take((size_t)256 * 768 * 2);
  u16* Wt1 = (u16*)take((size_t)256 * 256 * 2);
  float* as0 = (float*)take((size_t)NN * 4);
  float* ad0 = (float*)take((size_t)NN * 4);
  float* as1 = (float*)take((size_t)NN * 4);
  float* ad1 = (float*)take((size_t)NN * 4);
  float* slots = (float*)take((size_t)NSLOT * SLOTW * 4);
  uint* bptr = (uint*)take((size_t)NBUCK * 4);
  uint* bnxt = (uint*)take((size_t)NBUCK * 4);
  uint* row_ptr = (uint*)take((size_t)(NN + 1) * 4);
  uint* tmp = (uint*)take((size_t)NBUCK * CAP * 4);
  u16* csr = (u16*)take((size_t)ETOT * 2);

  const int* edge_src = edge;
  const int* edge_dst = edge + EE;

  zero_ws<<<(NSLOT * SLOTW + 255) / 256, 256, 0, stream>>>(bnxt, slots);
  wt_both<<<1024, 256, 0, stream>>>(W0, W1, Wt0, Wt1);

  bucket_scatter<<<(ETOT + ACHUNK - 1) / ACHUNK, 256, 0, stream>>>(edge_src, edge_dst, bnxt, tmp);
  scanb_kernel<<<1, 1024, 0, stream>>>(bnxt, bptr);
  bucket_sort<<<NBUCK, 256, 0, stream>>>(tmp, bptr, bnxt, row_ptr, csr);

  const int ggrid = (NN + 127) / 128;
  gemm_fused<false><<<ggrid, 512, 0, stream>>>(x, Wt0, hA, a_src0, a_dst0, as0, ad0, NN, 768);
  agg_kernel<false><<<12500, 256, 0, stream>>>((const uint*)hA, as0, ad0, row_ptr, csr, b0, hB,
                                               gate_w, slots, NN);
  gemm_fused<true><<<ggrid, 512, 0, stream>>>(hB, Wt1, hA, a_src1, a_dst1, as1, ad1, NN, 256);
  agg_kernel<true><<<12500, 256, 0, stream>>>((const uint*)hA, as1, ad1, row_ptr, csr, b1, nullptr,
                                              gate_w, slots, NN);

  pool3_kernel<<<1, 256, 0, stream>>>(slots, out);
}

// Round 7
// 282.893 us; speedup vs baseline: 3.1979x; 1.0362x over previous
//
#include <hip/hip_runtime.h>

typedef unsigned int uint;
typedef unsigned short u16;
typedef unsigned char u8;

typedef __attribute__((ext_vector_type(8))) short short8;
typedef __attribute__((ext_vector_type(8))) u16 u16x8;
typedef __attribute__((ext_vector_type(4))) float f32x4;
typedef __attribute__((ext_vector_type(2))) float f32x2;

#define NN 50000
#define EE 1600000
#define ETOT (EE + NN)
#define NBUCK 782            // ceil(NN/64)
#define ACHUNK 8192
#define CAP 2432             // per-bucket capacity (mean 2112, +7 sigma)
#define NSLOT 64
#define SLOTW 260            // 256 cols + denom @256, padded

__device__ __forceinline__ u16 f2bf(float f) {
  uint u = __builtin_bit_cast(uint, f);
  uint r = u + 0x7fffu + ((u >> 16) & 1u);
  return (u16)(r >> 16);
}
__device__ __forceinline__ float bf2f(u16 h) {
  return __builtin_bit_cast(float, ((uint)h) << 16);
}
__device__ __forceinline__ u8 f2fp8(float f) {
  int t = __builtin_amdgcn_cvt_pk_fp8_f32(f, f, 0, false);
  return (u8)(t & 0xff);
}
__device__ __forceinline__ float wred_sum(float v) {
#pragma unroll
  for (int off = 32; off > 0; off >>= 1) v += __shfl_xor(v, off);
  return v;
}

// ---------------- zero: bnxt + pool slots ----------------
__global__ void zero_ws(uint* __restrict__ bnxt, float* __restrict__ slots) {
  int i = blockIdx.x * 256 + threadIdx.x;
  if (i < NBUCK) bnxt[i] = 0u;
  if (i < NSLOT * SLOTW) slots[i] = 0.f;
}

// ---------------- W0+W1 transpose + bf16 convert ----------------
__global__ void wt_both(const float* __restrict__ W0, const float* __restrict__ W1,
                        u16* __restrict__ Wt0, u16* __restrict__ Wt1) {
  int i = blockIdx.x * 256 + threadIdx.x;
  if (i < 768 * 256) {
    int k = i >> 8, n = i & 255;
    Wt0[n * 768 + k] = f2bf(W0[i]);
  } else if (i < 768 * 256 + 256 * 256) {
    int j = i - 768 * 256;
    int k = j >> 8, n = j & 255;
    Wt1[n * 256 + k] = f2bf(W1[j]);
  }
}

// ---------------- GEMM + fused alpha epilogue; C written as fp8 e4m3 ----------------
template <bool ABF16>
__global__ __launch_bounds__(512) void gemm_fused(const void* __restrict__ Avoid,
                                                  const u16* __restrict__ Bt,
                                                  u8* __restrict__ C8,
                                                  const float* __restrict__ a_src,
                                                  const float* __restrict__ a_dst,
                                                  float* __restrict__ as_,
                                                  float* __restrict__ ad_,
                                                  int M, int K) {
  __shared__ __align__(16) u16 As[128 * 64];
  __shared__ __align__(16) u16 Bs[256 * 64];
  __shared__ float asLds[4][128];
  __shared__ float adLds[4][128];
  const int m0 = blockIdx.x * 128;
  const int tid = threadIdx.x;
  const int lane = tid & 63;
  const int wv = tid >> 6;
  const int wm = wv >> 2, wn = wv & 3;

  f32x4 acc[4][4] = {};

  const int sr = tid >> 2;
  const int skc = (tid & 3) * 16;
  const int br = tid >> 1;
  const int bk = (tid & 1) * 32;

  for (int k0 = 0; k0 < K; k0 += 64) {
    {
      int grow = m0 + sr;
      if constexpr (!ABF16) {
        const float* A = (const float*)Avoid;
        float4 f[4];
        if (grow < M) {
          const float4* src = reinterpret_cast<const float4*>(A + (size_t)grow * K + k0 + skc);
#pragma unroll
          for (int i = 0; i < 4; ++i) f[i] = src[i];
        } else {
#pragma unroll
          for (int i = 0; i < 4; ++i) f[i] = make_float4(0.f, 0.f, 0.f, 0.f);
        }
#pragma unroll
        for (int i = 0; i < 2; ++i) {
          u16x8 v;
          v[0] = f2bf(f[2 * i].x); v[1] = f2bf(f[2 * i].y);
          v[2] = f2bf(f[2 * i].z); v[3] = f2bf(f[2 * i].w);
          v[4] = f2bf(f[2 * i + 1].x); v[5] = f2bf(f[2 * i + 1].y);
          v[6] = f2bf(f[2 * i + 1].z); v[7] = f2bf(f[2 * i + 1].w);
          int k = skc + i * 8;
          int idx = (sr << 6) + (k ^ ((sr & 7) << 3));
          *reinterpret_cast<u16x8*>(&As[idx]) = v;
        }
      } else {
        const u16* A = (const u16*)Avoid;
        u16x8 v[2];
        if (grow < M) {
          const u16x8* src = reinterpret_cast<const u16x8*>(A + (size_t)grow * K + k0 + skc);
          v[0] = src[0]; v[1] = src[1];
        } else {
          v[0] = (u16x8)0; v[1] = (u16x8)0;
        }
#pragma unroll
        for (int i = 0; i < 2; ++i) {
          int k = skc + i * 8;
          int idx = (sr << 6) + (k ^ ((sr & 7) << 3));
          *reinterpret_cast<u16x8*>(&As[idx]) = v[i];
        }
      }
    }
    {
      const u16x8* src = reinterpret_cast<const u16x8*>(Bt + (size_t)br * K + k0 + bk);
#pragma unroll
      for (int i = 0; i < 4; ++i) {
        u16x8 v = src[i];
        int k = bk + i * 8;
        int idx = (br << 6) + (k ^ ((br & 7) << 3));
        *reinterpret_cast<u16x8*>(&Bs[idx]) = v;
      }
    }
    __syncthreads();
#pragma unroll
    for (int kk = 0; kk < 2; ++kk) {
      short8 af[4], bfr[4];
      const int kb = kk * 32 + (lane >> 4) * 8;
#pragma unroll
      for (int m = 0; m < 4; ++m) {
        int r = wm * 64 + m * 16 + (lane & 15);
        int idx = (r << 6) + (kb ^ ((r & 7) << 3));
        af[m] = *reinterpret_cast<const short8*>(&As[idx]);
      }
#pragma unroll
      for (int n = 0; n < 4; ++n) {
        int c = wn * 64 + n * 16 + (lane & 15);
        int idx = (c << 6) + (kb ^ ((c & 7) << 3));
        bfr[n] = *reinterpret_cast<const short8*>(&Bs[idx]);
      }
#pragma unroll
      for (int m = 0; m < 4; ++m)
#pragma unroll
        for (int n = 0; n < 4; ++n)
          acc[m][n] = __builtin_amdgcn_mfma_f32_16x16x32_bf16(af[m], bfr[n], acc[m][n], 0, 0, 0);
    }
    __syncthreads();
  }

  const int g = lane >> 4;
  const int cl = lane & 15;
  float asv[4], adv[4];
#pragma unroll
  for (int n = 0; n < 4; ++n) {
    int c = wn * 64 + n * 16 + cl;
    asv[n] = a_src[c];
    adv[n] = a_dst[c];
  }
#pragma unroll
  for (int m = 0; m < 4; ++m) {
#pragma unroll
    for (int reg = 0; reg < 4; ++reg) {
      int rl = wm * 64 + m * 16 + g * 4 + reg;
      int row = m0 + rl;
      float ps = 0.f, pd = 0.f;
      if (row < M) {
#pragma unroll
        for (int n = 0; n < 4; ++n) {
          float v = acc[m][n][reg];
          C8[(size_t)row * 256 + wn * 64 + n * 16 + cl] = f2fp8(v);
          ps = fmaf(v, asv[n], ps);
          pd = fmaf(v, adv[n], pd);
        }
      }
#pragma unroll
      for (int off = 1; off < 16; off <<= 1) {
        ps += __shfl_xor(ps, off);
        pd += __shfl_xor(pd, off);
      }
      if (cl == 0) {
        asLds[wn][rl] = ps;
        adLds[wn][rl] = pd;
      }
    }
  }
  __syncthreads();
  if (tid < 128) {
    int row = m0 + tid;
    if (row < M) {
      as_[row] = asLds[0][tid] + asLds[1][tid] + asLds[2][tid] + asLds[3][tid];
      ad_[row] = adLds[0][tid] + adLds[1][tid] + adLds[2][tid] + adLds[3][tid];
    }
  }
}

// ---------------- CSR build: fixed-capacity bucket scatter (no pre-histogram) ----------------
__global__ __launch_bounds__(256) void bucket_scatter(const int* __restrict__ esrc,
                                                      const int* __restrict__ edst,
                                                      uint* __restrict__ bnxt,
                                                      uint* __restrict__ tmp) {
  __shared__ uint lh[NBUCK];
  int base = blockIdx.x * ACHUNK;
  int nE = ETOT - base; if (nE > ACHUNK) nE = ACHUNK;
  for (int i = threadIdx.x; i < NBUCK; i += 256) lh[i] = 0;
  __syncthreads();
  for (int k = threadIdx.x; k < nE; k += 256) {
    int e = base + k;
    int d = (e < EE) ? edst[e] : (e - EE);
    atomicAdd(&lh[d >> 6], 1u);
  }
  __syncthreads();
  for (int i = threadIdx.x; i < NBUCK; i += 256) {
    uint c = lh[i];
    lh[i] = c ? atomicAdd(&bnxt[i], c) : 0u;
  }
  __syncthreads();
  for (int k = threadIdx.x; k < nE; k += 256) {
    int e = base + k;
    int s, d;
    if (e < EE) { s = esrc[e]; d = edst[e]; } else { s = e - EE; d = s; }
    uint pos = atomicAdd(&lh[d >> 6], 1u);
    tmp[(size_t)(d >> 6) * CAP + pos] = ((uint)(d & 63) << 16) | (uint)s;
  }
}

// exclusive scan of bucket counts (bnxt, post-scatter) -> bptr
__global__ __launch_bounds__(1024) void scanb_kernel(const uint* __restrict__ bnxt,
                                                     uint* __restrict__ bptr) {
  __shared__ uint wsum[16];
  int tid = threadIdx.x, lane = tid & 63, w = tid >> 6;
  uint v = (tid < NBUCK) ? bnxt[tid] : 0u;
  uint x = v;
#pragma unroll
  for (int off = 1; off < 64; off <<= 1) {
    uint t = __shfl_up(x, off);
    if (lane >= off) x += t;
  }
  if (lane == 63) wsum[w] = x;
  __syncthreads();
  uint woff = 0;
  for (int k = 0; k < w; ++k) woff += wsum[k];
  uint excl = woff + x - v;
  if (tid < NBUCK) bptr[tid] = excl;
}

// per-bucket 64-bin counting sort -> final csr (u16) + row_ptr
__global__ __launch_bounds__(256) void bucket_sort(const uint* __restrict__ tmp,
                                                   const uint* __restrict__ bptr,
                                                   const uint* __restrict__ bnxt,
                                                   uint* __restrict__ row_ptr,
                                                   u16* __restrict__ csr) {
  __shared__ uint lh[64];
  __shared__ uint buf[CAP];
  int b = blockIdx.x;
  uint s0 = bptr[b];
  int cnt = (int)bnxt[b];
  int tid = threadIdx.x;
  if (tid < 64) lh[tid] = 0;
  __syncthreads();
  for (int i = tid; i < cnt; i += 256) {
    uint v = tmp[(size_t)b * CAP + i];
    buf[i] = v;
    atomicAdd(&lh[v >> 16], 1u);
  }
  __syncthreads();
  if (tid < 64) {
    uint v = lh[tid];
    uint x = v;
#pragma unroll
    for (int off = 1; off < 64; off <<= 1) {
      uint t = __shfl_up(x, off);
      if (tid >= off) x += t;
    }
    uint pos = s0 + x - v;
    int d = b * 64 + tid;
    if (d < NN) row_ptr[d] = pos;
    lh[tid] = pos;
    if (b == NBUCK - 1 && tid == 0) row_ptr[NN] = s0 + (uint)cnt;
  }
  __syncthreads();
  for (int i = tid; i < cnt; i += 256) {
    uint v = buf[i];
    uint pos = atomicAdd(&lh[v >> 16], 1u);
    csr[pos] = (u16)(v & 0xFFFFu);
  }
}

// decode 16 fp8 from uint4 and fma into acc[16] with weight wg
#define FMA16(v, wg)                                                                   \
  do {                                                                                 \
    f32x2 p_;                                                                          \
    p_ = __builtin_amdgcn_cvt_pk_f32_fp8((v).x, false);                                \
    acc[0] = fmaf((wg), p_.x, acc[0]); acc[1] = fmaf((wg), p_.y, acc[1]);              \
    p_ = __builtin_amdgcn_cvt_pk_f32_fp8((v).x, true);                                 \
    acc[2] = fmaf((wg), p_.x, acc[2]); acc[3] = fmaf((wg), p_.y, acc[3]);              \
    p_ = __builtin_amdgcn_cvt_pk_f32_fp8((v).y, false);                                \
    acc[4] = fmaf((wg), p_.x, acc[4]); acc[5] = fmaf((wg), p_.y, acc[5]);              \
    p_ = __builtin_amdgcn_cvt_pk_f32_fp8((v).y, true);                                 \
    acc[6] = fmaf((wg), p_.x, acc[6]); acc[7] = fmaf((wg), p_.y, acc[7]);              \
    p_ = __builtin_amdgcn_cvt_pk_f32_fp8((v).z, false);                                \
    acc[8] = fmaf((wg), p_.x, acc[8]); acc[9] = fmaf((wg), p_.y, acc[9]);              \
    p_ = __builtin_amdgcn_cvt_pk_f32_fp8((v).z, true);                                 \
    acc[10] = fmaf((wg), p_.x, acc[10]); acc[11] = fmaf((wg), p_.y, acc[11]);          \
    p_ = __builtin_amdgcn_cvt_pk_f32_fp8((v).w, false);                                \
    acc[12] = fmaf((wg), p_.x, acc[12]); acc[13] = fmaf((wg), p_.y, acc[13]);          \
    p_ = __builtin_amdgcn_cvt_pk_f32_fp8((v).w, true);                                 \
    acc[14] = fmaf((wg), p_.x, acc[14]); acc[15] = fmaf((wg), p_.y, acc[15]);          \
  } while (0)

// ---------------- GAT aggregation (fp8 gather, 4 edges/instr); POOL fuses pooling ----------------
template <bool POOL>
__global__ __launch_bounds__(256) void agg_kernel(const uint4* __restrict__ h16,
                                                  const float* __restrict__ as_,
                                                  const float* __restrict__ ad_,
                                                  const uint* __restrict__ row_ptr,
                                                  const u16* __restrict__ csr_src,
                                                  const float* __restrict__ bias,
                                                  u16* __restrict__ out,
                                                  const float* __restrict__ gate_w,
                                                  float* __restrict__ slots, int n) {
  __shared__ float tr[4][4][16][16];   // [wave][group][li][col]
  __shared__ float lp[257];
  int wv = threadIdx.x >> 6;
  int wid = blockIdx.x * 4 + wv;
  int lane = threadIdx.x & 63;
  int g = lane >> 4, li = lane & 15;
  if (POOL) {
    for (int i = threadIdx.x; i < 257; i += 256) lp[i] = 0.f;
    __syncthreads();
  }
  if (wid < n) {
    uint start = row_ptr[wid], end = row_ptr[wid + 1];
    float adi = ad_[wid];
    float acc[16];
#pragma unroll
    for (int c = 0; c < 16; ++c) acc[c] = 0.f;
    float denom = 0.f;
    for (uint base = start; base < end; base += 64) {
      int cnt = (int)(end - base);
      if (cnt > 64) cnt = 64;
      float w = 0.f;
      int s = 0;
      if (lane < cnt) {
        s = (int)csr_src[base + lane];
        float e = as_[s] + adi;
        e = e > 0.f ? e : 0.2f * e;
        w = __expf(e);
      }
      denom += w;
      int j = 0;
      for (; j + 8 <= cnt; j += 8) {
        int s0 = __shfl(s, j + g);
        int s1 = __shfl(s, j + 4 + g);
        float w0 = __shfl(w, j + g);
        float w1 = __shfl(w, j + 4 + g);
        uint4 v0 = h16[(size_t)s0 * 16 + li];
        uint4 v1 = h16[(size_t)s1 * 16 + li];
        FMA16(v0, w0);
        FMA16(v1, w1);
      }
      for (; j < cnt; j += 4) {
        int jg = j + g;
        int sg = __shfl(s, jg & 63);
        float wg = __shfl(w, jg & 63);
        if (jg >= cnt) wg = 0.f;
        uint4 v = h16[(size_t)sg * 16 + li];
        FMA16(v, wg);
      }
    }
    denom = wred_sum(denom);
    // per-wave LDS transpose: [group][li][16 cols] -> 4 cols per lane
    *reinterpret_cast<float4*>(&tr[wv][g][li][0])  = make_float4(acc[0], acc[1], acc[2], acc[3]);
    *reinterpret_cast<float4*>(&tr[wv][g][li][4])  = make_float4(acc[4], acc[5], acc[6], acc[7]);
    *reinterpret_cast<float4*>(&tr[wv][g][li][8])  = make_float4(acc[8], acc[9], acc[10], acc[11]);
    *reinterpret_cast<float4*>(&tr[wv][g][li][12]) = make_float4(acc[12], acc[13], acc[14], acc[15]);
    asm volatile("s_waitcnt lgkmcnt(0)" ::: "memory");
    __builtin_amdgcn_sched_barrier(0);
    float ax = 0.f, ay = 0.f, az = 0.f, aw = 0.f;
#pragma unroll
    for (int gg = 0; gg < 4; ++gg) {
      float4 rv = *reinterpret_cast<const float4*>(&tr[wv][gg][lane >> 2][4 * (lane & 3)]);
      ax += rv.x; ay += rv.y; az += rv.z; aw += rv.w;
    }
    float inv = 1.f / (denom + 1e-16f);
    float4 b = reinterpret_cast<const float4*>(bias)[lane];
    float ox = fmaxf(fmaf(ax, inv, b.x), 0.f);
    float oy = fmaxf(fmaf(ay, inv, b.y), 0.f);
    float oz = fmaxf(fmaf(az, inv, b.z), 0.f);
    float ow = fmaxf(fmaf(aw, inv, b.w), 0.f);
    if (!POOL) {
      ushort4 o;
      o.x = f2bf(ox); o.y = f2bf(oy); o.z = f2bf(oz); o.w = f2bf(ow);
      reinterpret_cast<ushort4*>(out)[(size_t)wid * 64 + lane] = o;
    } else {
      float4 gv = reinterpret_cast<const float4*>(gate_w)[lane];
      float pg = wred_sum(ox * gv.x + oy * gv.y + oz * gv.z + ow * gv.w);
      float we = __expf(pg);
      int c0 = lane * 4;
      atomicAdd(&lp[c0 + 0], we * ox);
      atomicAdd(&lp[c0 + 1], we * oy);
      atomicAdd(&lp[c0 + 2], we * oz);
      atomicAdd(&lp[c0 + 3], we * ow);
      if (lane == 0) atomicAdd(&lp[256], we);
    }
  }
  if (POOL) {
    __syncthreads();
    int slot = blockIdx.x & (NSLOT - 1);
    for (int i = threadIdx.x; i < 257; i += 256) {
      float v = lp[i];
      if (v != 0.f) atomicAdd(&slots[slot * SLOTW + i], v);
    }
  }
}

// ---------------- final: reduce slots, normalize ----------------
__global__ void pool3_kernel(const float* __restrict__ slots, float* __restrict__ out) {
  __shared__ float dsh;
  int tid = threadIdx.x;
  float acc = 0.f;
  for (int s = 0; s < NSLOT; ++s) acc += slots[s * SLOTW + tid];
  if (tid == 0) {
    float d = 0.f;
    for (int s = 0; s < NSLOT; ++s) d += slots[s * SLOTW + 256];
    dsh = d;
  }
  __syncthreads();
  out[tid] = acc / dsh;
}

// ---------------- launch ----------------
extern "C" void kernel_launch(void* const* d_in, const int* in_sizes, int n_in,
                              void* d_out, int out_size, void* d_ws, size_t ws_size,
                              hipStream_t stream) {
  const float* x = (const float*)d_in[0];
  const int* edge = (const int*)d_in[1];
  const float* W0 = (const float*)d_in[2];
  const float* a_src0 = (const float*)d_in[3];
  const float* a_dst0 = (const float*)d_in[4];
  const float* b0 = (const float*)d_in[5];
  const float* W1 = (const float*)d_in[6];
  const float* a_src1 = (const float*)d_in[7];
  const float* a_dst1 = (const float*)d_in[8];
  const float* b1 = (const float*)d_in[9];
  const float* gate_w = (const float*)d_in[10];
  float* out = (float*)d_out;

  char* p = (char*)d_ws;
  size_t off = 0;
  auto take = [&](size_t bytes) -> char* {
    char* r = p + off;
    off = (off + bytes + 255) & ~(size_t)255;
    return r;
  };
  u8* hA = (u8*)take((size_t)NN * 256);          // fp8 h (GEMM out, gather operand)
  u16* hB = (u16*)take((size_t)NN * 256 * 2);    // bf16 agg0 out (gemm1 input)
  u16* Wt0 = (u16*)take((size_t)256 * 768 * 2);
  u16* Wt1 = (u16*)take((size_t)256 * 256 * 2);
  float* as0 = (float*)take((size_t)NN * 4);
  float* ad0 = (float*)take((size_t)NN * 4);
  float* as1 = (float*)take((size_t)NN * 4);
  float* ad1 = (float*)take((size_t)NN * 4);
  float* slots = (float*)take((size_t)NSLOT * SLOTW * 4);
  uint* bptr = (uint*)take((size_t)NBUCK * 4);
  uint* bnxt = (uint*)take((size_t)NBUCK * 4);
  uint* row_ptr = (uint*)take((size_t)(NN + 1) * 4);
  uint* tmp = (uint*)take((size_t)NBUCK * CAP * 4);
  u16* csr = (u16*)take((size_t)ETOT * 2);

  const int* edge_src = edge;
  const int* edge_dst = edge + EE;

  zero_ws<<<(NSLOT * SLOTW + 255) / 256, 256, 0, stream>>>(bnxt, slots);
  wt_both<<<1024, 256, 0, stream>>>(W0, W1, Wt0, Wt1);

  bucket_scatter<<<(ETOT + ACHUNK - 1) / ACHUNK, 256, 0, stream>>>(edge_src, edge_dst, bnxt, tmp);
  scanb_kernel<<<1, 1024, 0, stream>>>(bnxt, bptr);
  bucket_sort<<<NBUCK, 256, 0, stream>>>(tmp, bptr, bnxt, row_ptr, csr);

  const int ggrid = (NN + 127) / 128;
  gemm_fused<false><<<ggrid, 512, 0, stream>>>(x, Wt0, hA, a_src0, a_dst0, as0, ad0, NN, 768);
  agg_kernel<false><<<12500, 256, 0, stream>>>((const uint4*)hA, as0, ad0, row_ptr, csr, b0, hB,
                                               gate_w, slots, NN);
  gemm_fused<true><<<ggrid, 512, 0, stream>>>(hB, Wt1, hA, a_src1, a_dst1, as1, ad1, NN, 256);
  agg_kernel<true><<<12500, 256, 0, stream>>>((const uint4*)hA, as1, ad1, row_ptr, csr, b1, nullptr,
                                              gate_w, slots, NN);

  pool3_kernel<<<1, 256, 0, stream>>>(slots, out);
}

// Round 8
// 282.775 us; speedup vs baseline: 3.1992x; 1.0004x over previous
//
#include <hip/hip_runtime.h>

typedef unsigned int uint;
typedef unsigned short u16;
typedef unsigned char u8;

typedef __attribute__((ext_vector_type(8))) short short8;
typedef __attribute__((ext_vector_type(8))) u16 u16x8;
typedef __attribute__((ext_vector_type(4))) float f32x4;
typedef __attribute__((ext_vector_type(2))) float f32x2;

#define NN 50000
#define EE 1600000
#define ETOT (EE + NN)
#define NBUCK 782            // ceil(NN/64)
#define ACHUNK 8192
#define CAP 2432             // per-bucket capacity (mean 2112, +7 sigma)
#define NSLOT 64
#define SLOTW 260            // 256 cols + denom @256, padded

__device__ __forceinline__ u16 f2bf(float f) {
  uint u = __builtin_bit_cast(uint, f);
  uint r = u + 0x7fffu + ((u >> 16) & 1u);
  return (u16)(r >> 16);
}
__device__ __forceinline__ float bf2f(u16 h) {
  return __builtin_bit_cast(float, ((uint)h) << 16);
}
__device__ __forceinline__ u8 f2fp8(float f) {
  int t = __builtin_amdgcn_cvt_pk_fp8_f32(f, f, 0, false);
  return (u8)(t & 0xff);
}
__device__ __forceinline__ float wred_sum(float v) {
#pragma unroll
  for (int off = 32; off > 0; off >>= 1) v += __shfl_xor(v, off);
  return v;
}

// ---------------- zero: bnxt + pool slots ----------------
__global__ void zero_ws(uint* __restrict__ bnxt, float* __restrict__ slots) {
  int i = blockIdx.x * 256 + threadIdx.x;
  if (i < NBUCK) bnxt[i] = 0u;
  if (i < NSLOT * SLOTW) slots[i] = 0.f;
}

// ---------------- W0+W1 transpose + bf16 convert ----------------
__global__ void wt_both(const float* __restrict__ W0, const float* __restrict__ W1,
                        u16* __restrict__ Wt0, u16* __restrict__ Wt1) {
  int i = blockIdx.x * 256 + threadIdx.x;
  if (i < 768 * 256) {
    int k = i >> 8, n = i & 255;
    Wt0[n * 768 + k] = f2bf(W0[i]);
  } else if (i < 768 * 256 + 256 * 256) {
    int j = i - 768 * 256;
    int k = j >> 8, n = j & 255;
    Wt1[n * 256 + k] = f2bf(W1[j]);
  }
}

// ---------------- GEMM + fused alpha epilogue; C written as fp8 e4m3 ----------------
template <bool ABF16>
__global__ __launch_bounds__(512) void gemm_fused(const void* __restrict__ Avoid,
                                                  const u16* __restrict__ Bt,
                                                  u8* __restrict__ C8,
                                                  const float* __restrict__ a_src,
                                                  const float* __restrict__ a_dst,
                                                  float* __restrict__ as_,
                                                  float* __restrict__ ad_,
                                                  int M, int K) {
  __shared__ __align__(16) u16 As[128 * 64];
  __shared__ __align__(16) u16 Bs[256 * 64];
  __shared__ float asLds[4][128];
  __shared__ float adLds[4][128];
  const int m0 = blockIdx.x * 128;
  const int tid = threadIdx.x;
  const int lane = tid & 63;
  const int wv = tid >> 6;
  const int wm = wv >> 2, wn = wv & 3;

  f32x4 acc[4][4] = {};

  const int sr = tid >> 2;
  const int skc = (tid & 3) * 16;
  const int br = tid >> 1;
  const int bk = (tid & 1) * 32;

  for (int k0 = 0; k0 < K; k0 += 64) {
    {
      int grow = m0 + sr;
      if constexpr (!ABF16) {
        const float* A = (const float*)Avoid;
        float4 f[4];
        if (grow < M) {
          const float4* src = reinterpret_cast<const float4*>(A + (size_t)grow * K + k0 + skc);
#pragma unroll
          for (int i = 0; i < 4; ++i) f[i] = src[i];
        } else {
#pragma unroll
          for (int i = 0; i < 4; ++i) f[i] = make_float4(0.f, 0.f, 0.f, 0.f);
        }
#pragma unroll
        for (int i = 0; i < 2; ++i) {
          u16x8 v;
          v[0] = f2bf(f[2 * i].x); v[1] = f2bf(f[2 * i].y);
          v[2] = f2bf(f[2 * i].z); v[3] = f2bf(f[2 * i].w);
          v[4] = f2bf(f[2 * i + 1].x); v[5] = f2bf(f[2 * i + 1].y);
          v[6] = f2bf(f[2 * i + 1].z); v[7] = f2bf(f[2 * i + 1].w);
          int k = skc + i * 8;
          int idx = (sr << 6) + (k ^ ((sr & 7) << 3));
          *reinterpret_cast<u16x8*>(&As[idx]) = v;
        }
      } else {
        const u16* A = (const u16*)Avoid;
        u16x8 v[2];
        if (grow < M) {
          const u16x8* src = reinterpret_cast<const u16x8*>(A + (size_t)grow * K + k0 + skc);
          v[0] = src[0]; v[1] = src[1];
        } else {
          v[0] = (u16x8)0; v[1] = (u16x8)0;
        }
#pragma unroll
        for (int i = 0; i < 2; ++i) {
          int k = skc + i * 8;
          int idx = (sr << 6) + (k ^ ((sr & 7) << 3));
          *reinterpret_cast<u16x8*>(&As[idx]) = v[i];
        }
      }
    }
    {
      const u16x8* src = reinterpret_cast<const u16x8*>(Bt + (size_t)br * K + k0 + bk);
#pragma unroll
      for (int i = 0; i < 4; ++i) {
        u16x8 v = src[i];
        int k = bk + i * 8;
        int idx = (br << 6) + (k ^ ((br & 7) << 3));
        *reinterpret_cast<u16x8*>(&Bs[idx]) = v;
      }
    }
    __syncthreads();
#pragma unroll
    for (int kk = 0; kk < 2; ++kk) {
      short8 af[4], bfr[4];
      const int kb = kk * 32 + (lane >> 4) * 8;
#pragma unroll
      for (int m = 0; m < 4; ++m) {
        int r = wm * 64 + m * 16 + (lane & 15);
        int idx = (r << 6) + (kb ^ ((r & 7) << 3));
        af[m] = *reinterpret_cast<const short8*>(&As[idx]);
      }
#pragma unroll
      for (int n = 0; n < 4; ++n) {
        int c = wn * 64 + n * 16 + (lane & 15);
        int idx = (c << 6) + (kb ^ ((c & 7) << 3));
        bfr[n] = *reinterpret_cast<const short8*>(&Bs[idx]);
      }
#pragma unroll
      for (int m = 0; m < 4; ++m)
#pragma unroll
        for (int n = 0; n < 4; ++n)
          acc[m][n] = __builtin_amdgcn_mfma_f32_16x16x32_bf16(af[m], bfr[n], acc[m][n], 0, 0, 0);
    }
    __syncthreads();
  }

  const int g = lane >> 4;
  const int cl = lane & 15;
  float asv[4], adv[4];
#pragma unroll
  for (int n = 0; n < 4; ++n) {
    int c = wn * 64 + n * 16 + cl;
    asv[n] = a_src[c];
    adv[n] = a_dst[c];
  }
#pragma unroll
  for (int m = 0; m < 4; ++m) {
#pragma unroll
    for (int reg = 0; reg < 4; ++reg) {
      int rl = wm * 64 + m * 16 + g * 4 + reg;
      int row = m0 + rl;
      float ps = 0.f, pd = 0.f;
      if (row < M) {
#pragma unroll
        for (int n = 0; n < 4; ++n) {
          float v = acc[m][n][reg];
          C8[(size_t)row * 256 + wn * 64 + n * 16 + cl] = f2fp8(v);
          ps = fmaf(v, asv[n], ps);
          pd = fmaf(v, adv[n], pd);
        }
      }
#pragma unroll
      for (int off = 1; off < 16; off <<= 1) {
        ps += __shfl_xor(ps, off);
        pd += __shfl_xor(pd, off);
      }
      if (cl == 0) {
        asLds[wn][rl] = ps;
        adLds[wn][rl] = pd;
      }
    }
  }
  __syncthreads();
  if (tid < 128) {
    int row = m0 + tid;
    if (row < M) {
      as_[row] = asLds[0][tid] + asLds[1][tid] + asLds[2][tid] + asLds[3][tid];
      ad_[row] = adLds[0][tid] + adLds[1][tid] + adLds[2][tid] + adLds[3][tid];
    }
  }
}

// ---------------- CSR build: fixed-capacity bucket scatter (no pre-histogram) ----------------
__global__ __launch_bounds__(256) void bucket_scatter(const int* __restrict__ esrc,
                                                      const int* __restrict__ edst,
                                                      uint* __restrict__ bnxt,
                                                      uint* __restrict__ tmp) {
  __shared__ uint lh[NBUCK];
  int base = blockIdx.x * ACHUNK;
  int nE = ETOT - base; if (nE > ACHUNK) nE = ACHUNK;
  for (int i = threadIdx.x; i < NBUCK; i += 256) lh[i] = 0;
  __syncthreads();
  for (int k = threadIdx.x; k < nE; k += 256) {
    int e = base + k;
    int d = (e < EE) ? edst[e] : (e - EE);
    atomicAdd(&lh[d >> 6], 1u);
  }
  __syncthreads();
  for (int i = threadIdx.x; i < NBUCK; i += 256) {
    uint c = lh[i];
    lh[i] = c ? atomicAdd(&bnxt[i], c) : 0u;
  }
  __syncthreads();
  for (int k = threadIdx.x; k < nE; k += 256) {
    int e = base + k;
    int s, d;
    if (e < EE) { s = esrc[e]; d = edst[e]; } else { s = e - EE; d = s; }
    uint pos = atomicAdd(&lh[d >> 6], 1u);
    tmp[(size_t)(d >> 6) * CAP + pos] = ((uint)(d & 63) << 16) | (uint)s;
  }
}

// exclusive scan of bucket counts (bnxt, post-scatter) -> bptr
__global__ __launch_bounds__(1024) void scanb_kernel(const uint* __restrict__ bnxt,
                                                     uint* __restrict__ bptr) {
  __shared__ uint wsum[16];
  int tid = threadIdx.x, lane = tid & 63, w = tid >> 6;
  uint v = (tid < NBUCK) ? bnxt[tid] : 0u;
  uint x = v;
#pragma unroll
  for (int off = 1; off < 64; off <<= 1) {
    uint t = __shfl_up(x, off);
    if (lane >= off) x += t;
  }
  if (lane == 63) wsum[w] = x;
  __syncthreads();
  uint woff = 0;
  for (int k = 0; k < w; ++k) woff += wsum[k];
  uint excl = woff + x - v;
  if (tid < NBUCK) bptr[tid] = excl;
}

// per-bucket 64-bin counting sort -> final csr (u16) + row_ptr
__global__ __launch_bounds__(256) void bucket_sort(const uint* __restrict__ tmp,
                                                   const uint* __restrict__ bptr,
                                                   const uint* __restrict__ bnxt,
                                                   uint* __restrict__ row_ptr,
                                                   u16* __restrict__ csr) {
  __shared__ uint lh[64];
  __shared__ uint buf[CAP];
  int b = blockIdx.x;
  uint s0 = bptr[b];
  int cnt = (int)bnxt[b];
  int tid = threadIdx.x;
  if (tid < 64) lh[tid] = 0;
  __syncthreads();
  for (int i = tid; i < cnt; i += 256) {
    uint v = tmp[(size_t)b * CAP + i];
    buf[i] = v;
    atomicAdd(&lh[v >> 16], 1u);
  }
  __syncthreads();
  if (tid < 64) {
    uint v = lh[tid];
    uint x = v;
#pragma unroll
    for (int off = 1; off < 64; off <<= 1) {
      uint t = __shfl_up(x, off);
      if (tid >= off) x += t;
    }
    uint pos = s0 + x - v;
    int d = b * 64 + tid;
    if (d < NN) row_ptr[d] = pos;
    lh[tid] = pos;
    if (b == NBUCK - 1 && tid == 0) row_ptr[NN] = s0 + (uint)cnt;
  }
  __syncthreads();
  for (int i = tid; i < cnt; i += 256) {
    uint v = buf[i];
    uint pos = atomicAdd(&lh[v >> 16], 1u);
    csr[pos] = (u16)(v & 0xFFFFu);
  }
}

// decode 16 fp8 from uint4 and fma into acc[16] with weight wg
#define FMA16(v, wg)                                                                   \
  do {                                                                                 \
    f32x2 p_;                                                                          \
    p_ = __builtin_amdgcn_cvt_pk_f32_fp8((v).x, false);                                \
    acc[0] = fmaf((wg), p_.x, acc[0]); acc[1] = fmaf((wg), p_.y, acc[1]);              \
    p_ = __builtin_amdgcn_cvt_pk_f32_fp8((v).x, true);                                 \
    acc[2] = fmaf((wg), p_.x, acc[2]); acc[3] = fmaf((wg), p_.y, acc[3]);              \
    p_ = __builtin_amdgcn_cvt_pk_f32_fp8((v).y, false);                                \
    acc[4] = fmaf((wg), p_.x, acc[4]); acc[5] = fmaf((wg), p_.y, acc[5]);              \
    p_ = __builtin_amdgcn_cvt_pk_f32_fp8((v).y, true);                                 \
    acc[6] = fmaf((wg), p_.x, acc[6]); acc[7] = fmaf((wg), p_.y, acc[7]);              \
    p_ = __builtin_amdgcn_cvt_pk_f32_fp8((v).z, false);                                \
    acc[8] = fmaf((wg), p_.x, acc[8]); acc[9] = fmaf((wg), p_.y, acc[9]);              \
    p_ = __builtin_amdgcn_cvt_pk_f32_fp8((v).z, true);                                 \
    acc[10] = fmaf((wg), p_.x, acc[10]); acc[11] = fmaf((wg), p_.y, acc[11]);          \
    p_ = __builtin_amdgcn_cvt_pk_f32_fp8((v).w, false);                                \
    acc[12] = fmaf((wg), p_.x, acc[12]); acc[13] = fmaf((wg), p_.y, acc[13]);          \
    p_ = __builtin_amdgcn_cvt_pk_f32_fp8((v).w, true);                                 \
    acc[14] = fmaf((wg), p_.x, acc[14]); acc[15] = fmaf((wg), p_.y, acc[15]);          \
  } while (0)

// ---------------- GAT aggregation (fp8 gather, 4 loads in flight); POOL fuses pooling ----------------
template <bool POOL>
__global__ __launch_bounds__(256) void agg_kernel(const uint4* __restrict__ h16,
                                                  const float* __restrict__ as_,
                                                  const float* __restrict__ ad_,
                                                  const uint* __restrict__ row_ptr,
                                                  const u16* __restrict__ csr_src,
                                                  const float* __restrict__ bias,
                                                  u16* __restrict__ out,
                                                  const float* __restrict__ gate_w,
                                                  float* __restrict__ slots, int n) {
  __shared__ float tr[4][4][16][17];   // [wave][group][li][col] (+1 pad: no bank conflicts)
  __shared__ float lp[257];
  int wv = threadIdx.x >> 6;
  int wid = blockIdx.x * 4 + wv;
  int lane = threadIdx.x & 63;
  int g = lane >> 4, li = lane & 15;
  if (POOL) {
    for (int i = threadIdx.x; i < 257; i += 256) lp[i] = 0.f;
    __syncthreads();
  }
  if (wid < n) {
    uint start = row_ptr[wid], end = row_ptr[wid + 1];
    float adi = ad_[wid];
    float acc[16];
#pragma unroll
    for (int c = 0; c < 16; ++c) acc[c] = 0.f;
    float denom = 0.f;
    for (uint base = start; base < end; base += 64) {
      int cnt = (int)(end - base);
      if (cnt > 64) cnt = 64;
      float w = 0.f;
      int s = 0;
      if (lane < cnt) {
        s = (int)csr_src[base + lane];
        float e = as_[s] + adi;
        e = e > 0.f ? e : 0.2f * e;
        w = __expf(e);
      }
      denom += w;
      int j = 0;
      // 16 edges per iter -> 4 independent dwordx4 loads in flight per lane
      for (; j + 16 <= cnt; j += 16) {
        int s0 = __shfl(s, j + g);
        int s1 = __shfl(s, j + 4 + g);
        int s2 = __shfl(s, j + 8 + g);
        int s3 = __shfl(s, j + 12 + g);
        float w0 = __shfl(w, j + g);
        float w1 = __shfl(w, j + 4 + g);
        float w2 = __shfl(w, j + 8 + g);
        float w3 = __shfl(w, j + 12 + g);
        uint4 v0 = h16[(size_t)s0 * 16 + li];
        uint4 v1 = h16[(size_t)s1 * 16 + li];
        uint4 v2 = h16[(size_t)s2 * 16 + li];
        uint4 v3 = h16[(size_t)s3 * 16 + li];
        FMA16(v0, w0);
        FMA16(v1, w1);
        FMA16(v2, w2);
        FMA16(v3, w3);
      }
      for (; j < cnt; j += 4) {
        int jg = j + g;
        int sg = __shfl(s, jg & 63);
        float wg = __shfl(w, jg & 63);
        if (jg >= cnt) wg = 0.f;
        uint4 v = h16[(size_t)sg * 16 + li];
        FMA16(v, wg);
      }
    }
    denom = wred_sum(denom);
    // per-wave LDS transpose: [group][li][16 cols] -> 4 cols per lane
#pragma unroll
    for (int c4 = 0; c4 < 4; ++c4)
      *reinterpret_cast<float4*>(&tr[wv][g][li][c4 * 4]) =
          make_float4(acc[c4 * 4], acc[c4 * 4 + 1], acc[c4 * 4 + 2], acc[c4 * 4 + 3]);
    asm volatile("s_waitcnt lgkmcnt(0)" ::: "memory");
    __builtin_amdgcn_sched_barrier(0);
    float ax = 0.f, ay = 0.f, az = 0.f, aw = 0.f;
#pragma unroll
    for (int gg = 0; gg < 4; ++gg) {
      const float* r = &tr[wv][gg][lane >> 2][4 * (lane & 3)];
      ax += r[0]; ay += r[1]; az += r[2]; aw += r[3];
    }
    float inv = 1.f / (denom + 1e-16f);
    float4 b = reinterpret_cast<const float4*>(bias)[lane];
    float ox = fmaxf(fmaf(ax, inv, b.x), 0.f);
    float oy = fmaxf(fmaf(ay, inv, b.y), 0.f);
    float oz = fmaxf(fmaf(az, inv, b.z), 0.f);
    float ow = fmaxf(fmaf(aw, inv, b.w), 0.f);
    if (!POOL) {
      ushort4 o;
      o.x = f2bf(ox); o.y = f2bf(oy); o.z = f2bf(oz); o.w = f2bf(ow);
      reinterpret_cast<ushort4*>(out)[(size_t)wid * 64 + lane] = o;
    } else {
      float4 gv = reinterpret_cast<const float4*>(gate_w)[lane];
      float pg = wred_sum(ox * gv.x + oy * gv.y + oz * gv.z + ow * gv.w);
      float we = __expf(pg);
      int c0 = lane * 4;
      atomicAdd(&lp[c0 + 0], we * ox);
      atomicAdd(&lp[c0 + 1], we * oy);
      atomicAdd(&lp[c0 + 2], we * oz);
      atomicAdd(&lp[c0 + 3], we * ow);
      if (lane == 0) atomicAdd(&lp[256], we);
    }
  }
  if (POOL) {
    __syncthreads();
    int slot = blockIdx.x & (NSLOT - 1);
    for (int i = threadIdx.x; i < 257; i += 256) {
      float v = lp[i];
      if (v != 0.f) atomicAdd(&slots[slot * SLOTW + i], v);
    }
  }
}

// ---------------- final: reduce slots, normalize ----------------
__global__ void pool3_kernel(const float* __restrict__ slots, float* __restrict__ out) {
  __shared__ float dsh;
  int tid = threadIdx.x;
  float acc = 0.f;
  for (int s = 0; s < NSLOT; ++s) acc += slots[s * SLOTW + tid];
  if (tid == 0) {
    float d = 0.f;
    for (int s = 0; s < NSLOT; ++s) d += slots[s * SLOTW + 256];
    dsh = d;
  }
  __syncthreads();
  out[tid] = acc / dsh;
}

// ---------------- launch ----------------
extern "C" void kernel_launch(void* const* d_in, const int* in_sizes, int n_in,
                              void* d_out, int out_size, void* d_ws, size_t ws_size,
                              hipStream_t stream) {
  const float* x = (const float*)d_in[0];
  const int* edge = (const int*)d_in[1];
  const float* W0 = (const float*)d_in[2];
  const float* a_src0 = (const float*)d_in[3];
  const float* a_dst0 = (const float*)d_in[4];
  const float* b0 = (const float*)d_in[5];
  const float* W1 = (const float*)d_in[6];
  const float* a_src1 = (const float*)d_in[7];
  const float* a_dst1 = (const float*)d_in[8];
  const float* b1 = (const float*)d_in[9];
  const float* gate_w = (const float*)d_in[10];
  float* out = (float*)d_out;

  char* p = (char*)d_ws;
  size_t off = 0;
  auto take = [&](size_t bytes) -> char* {
    char* r = p + off;
    off = (off + bytes + 255) & ~(size_t)255;
    return r;
  };
  u8* hA = (u8*)take((size_t)NN * 256);          // fp8 h (GEMM out, gather operand)
  u16* hB = (u16*)take((size_t)NN * 256 * 2);    // bf16 agg0 out (gemm1 input)
  u16* Wt0 = (u16*)take((size_t)256 * 768 * 2);
  u16* Wt1 = (u16*)take((size_t)256 * 256 * 2);
  float* as0 = (float*)take((size_t)NN * 4);
  float* ad0 = (float*)take((size_t)NN * 4);
  float* as1 = (float*)take((size_t)NN * 4);
  float* ad1 = (float*)take((size_t)NN * 4);
  float* slots = (float*)take((size_t)NSLOT * SLOTW * 4);
  uint* bptr = (uint*)take((size_t)NBUCK * 4);
  uint* bnxt = (uint*)take((size_t)NBUCK * 4);
  uint* row_ptr = (uint*)take((size_t)(NN + 1) * 4);
  uint* tmp = (uint*)take((size_t)NBUCK * CAP * 4);
  u16* csr = (u16*)take((size_t)ETOT * 2);

  const int* edge_src = edge;
  const int* edge_dst = edge + EE;

  zero_ws<<<(NSLOT * SLOTW + 255) / 256, 256, 0, stream>>>(bnxt, slots);
  wt_both<<<1024, 256, 0, stream>>>(W0, W1, Wt0, Wt1);

  bucket_scatter<<<(ETOT + ACHUNK - 1) / ACHUNK, 256, 0, stream>>>(edge_src, edge_dst, bnxt, tmp);
  scanb_kernel<<<1, 1024, 0, stream>>>(bnxt, bptr);
  bucket_sort<<<NBUCK, 256, 0, stream>>>(tmp, bptr, bnxt, row_ptr, csr);

  const int ggrid = (NN + 127) / 128;
  gemm_fused<false><<<ggrid, 512, 0, stream>>>(x, Wt0, hA, a_src0, a_dst0, as0, ad0, NN, 768);
  agg_kernel<false><<<12500, 256, 0, stream>>>((const uint4*)hA, as0, ad0, row_ptr, csr, b0, hB,
                                               gate_w, slots, NN);
  gemm_fused<true><<<ggrid, 512, 0, stream>>>(hB, Wt1, hA, a_src1, a_dst1, as1, ad1, NN, 256);
  agg_kernel<true><<<12500, 256, 0, stream>>>((const uint4*)hA, as1, ad1, row_ptr, csr, b1, nullptr,
                                              gate_w, slots, NN);

  pool3_kernel<<<1, 256, 0, stream>>>(slots, out);
}

// Round 9
// 277.762 us; speedup vs baseline: 3.2570x; 1.0180x over previous
//
#include <hip/hip_runtime.h>

typedef unsigned int uint;
typedef unsigned short u16;
typedef unsigned char u8;

typedef __attribute__((ext_vector_type(8))) short short8;
typedef __attribute__((ext_vector_type(8))) u16 u16x8;
typedef __attribute__((ext_vector_type(4))) float f32x4;
typedef __attribute__((ext_vector_type(2))) float f32x2;

#define NN 50000
#define EE 1600000
#define ETOT (EE + NN)
#define NBUCK 782            // ceil(NN/64)
#define ACHUNK 8192
#define NSC ((ETOT + ACHUNK - 1) / ACHUNK)   // scatter blocks = 202
#define CAP 2432             // per-bucket capacity (mean 2112, +7 sigma)
#define NSLOT 64
#define SLOTW 260
#define GEMM_BLOCKS ((NN + 127) / 128)       // 391

__device__ __forceinline__ u16 f2bf(float f) {
  uint u = __builtin_bit_cast(uint, f);
  uint r = u + 0x7fffu + ((u >> 16) & 1u);
  return (u16)(r >> 16);
}
__device__ __forceinline__ u8 f2fp8(float f) {
  int t = __builtin_amdgcn_cvt_pk_fp8_f32(f, f, 0, false);
  return (u8)(t & 0xff);
}
__device__ __forceinline__ float wred_sum(float v) {
#pragma unroll
  for (int off = 32; off > 0; off >>= 1) v += __shfl_xor(v, off);
  return v;
}
__device__ __forceinline__ uint wred_sum_u(uint v) {
#pragma unroll
  for (int off = 32; off > 0; off >>= 1) v += __shfl_xor(v, off);
  return v;
}

// ---------------- zero: bnxt + pool slots ----------------
__global__ void zero_ws(uint* __restrict__ bnxt, float* __restrict__ slots) {
  int t = threadIdx.x;
  for (int i = t; i < NBUCK; i += 1024) bnxt[i] = 0u;
  for (int i = t; i < NSLOT * SLOTW; i += 1024) slots[i] = 0.f;
}

// ---------------- fused: bucket scatter (blocks < NSC) + W transpose (rest) ----------------
__global__ __launch_bounds__(256) void scat_wt(const int* __restrict__ esrc,
                                               const int* __restrict__ edst,
                                               uint* __restrict__ bnxt,
                                               uint* __restrict__ tmp,
                                               const float* __restrict__ W0,
                                               const float* __restrict__ W1,
                                               u16* __restrict__ Wt0,
                                               u16* __restrict__ Wt1) {
  __shared__ uint lh[NBUCK];
  if (blockIdx.x < NSC) {
    int base = blockIdx.x * ACHUNK;
    int nE = ETOT - base; if (nE > ACHUNK) nE = ACHUNK;
    for (int i = threadIdx.x; i < NBUCK; i += 256) lh[i] = 0;
    __syncthreads();
    for (int k = threadIdx.x; k < nE; k += 256) {
      int e = base + k;
      int d = (e < EE) ? edst[e] : (e - EE);
      atomicAdd(&lh[d >> 6], 1u);
    }
    __syncthreads();
    for (int i = threadIdx.x; i < NBUCK; i += 256) {
      uint c = lh[i];
      lh[i] = c ? atomicAdd(&bnxt[i], c) : 0u;
    }
    __syncthreads();
    for (int k = threadIdx.x; k < nE; k += 256) {
      int e = base + k;
      int s, d;
      if (e < EE) { s = esrc[e]; d = edst[e]; } else { s = e - EE; d = s; }
      uint pos = atomicAdd(&lh[d >> 6], 1u);
      tmp[(size_t)(d >> 6) * CAP + pos] = ((uint)(d & 63) << 16) | (uint)s;
    }
  } else {
    int i = (blockIdx.x - NSC) * 256 + threadIdx.x;
    if (i < 768 * 256) {
      int k = i >> 8, n = i & 255;
      Wt0[n * 768 + k] = f2bf(W0[i]);
    } else if (i < 768 * 256 + 256 * 256) {
      int j = i - 768 * 256;
      int k = j >> 8, n = j & 255;
      Wt1[n * 256 + k] = f2bf(W1[j]);
    }
  }
}

// ---------------- GEMM body (shared-arena based) ----------------
template <bool ABF16>
__device__ __forceinline__ void gemm_body(char* smem, int bx, const void* __restrict__ Avoid,
                                          const u16* __restrict__ Bt, u8* __restrict__ C8,
                                          const float* __restrict__ a_src,
                                          const float* __restrict__ a_dst,
                                          float* __restrict__ as_, float* __restrict__ ad_,
                                          int M, int K) {
  u16* As = (u16*)smem;                      // 16384 B
  u16* Bs = (u16*)(smem + 16384);            // 32768 B
  float* asL = (float*)(smem + 49152);       // 2048 B
  float* adL = (float*)(smem + 51200);       // 2048 B
  const int m0 = bx * 128;
  const int tid = threadIdx.x;
  const int lane = tid & 63;
  const int wv = tid >> 6;
  const int wm = wv >> 2, wn = wv & 3;

  f32x4 acc[4][4] = {};

  const int sr = tid >> 2;
  const int skc = (tid & 3) * 16;
  const int br = tid >> 1;
  const int bk = (tid & 1) * 32;

  for (int k0 = 0; k0 < K; k0 += 64) {
    {
      int grow = m0 + sr;
      if constexpr (!ABF16) {
        const float* A = (const float*)Avoid;
        float4 f[4];
        if (grow < M) {
          const float4* src = reinterpret_cast<const float4*>(A + (size_t)grow * K + k0 + skc);
#pragma unroll
          for (int i = 0; i < 4; ++i) f[i] = src[i];
        } else {
#pragma unroll
          for (int i = 0; i < 4; ++i) f[i] = make_float4(0.f, 0.f, 0.f, 0.f);
        }
#pragma unroll
        for (int i = 0; i < 2; ++i) {
          u16x8 v;
          v[0] = f2bf(f[2 * i].x); v[1] = f2bf(f[2 * i].y);
          v[2] = f2bf(f[2 * i].z); v[3] = f2bf(f[2 * i].w);
          v[4] = f2bf(f[2 * i + 1].x); v[5] = f2bf(f[2 * i + 1].y);
          v[6] = f2bf(f[2 * i + 1].z); v[7] = f2bf(f[2 * i + 1].w);
          int k = skc + i * 8;
          int idx = (sr << 6) + (k ^ ((sr & 7) << 3));
          *reinterpret_cast<u16x8*>(&As[idx]) = v;
        }
      } else {
        const u16* A = (const u16*)Avoid;
        u16x8 v[2];
        if (grow < M) {
          const u16x8* src = reinterpret_cast<const u16x8*>(A + (size_t)grow * K + k0 + skc);
          v[0] = src[0]; v[1] = src[1];
        } else {
          v[0] = (u16x8)0; v[1] = (u16x8)0;
        }
#pragma unroll
        for (int i = 0; i < 2; ++i) {
          int k = skc + i * 8;
          int idx = (sr << 6) + (k ^ ((sr & 7) << 3));
          *reinterpret_cast<u16x8*>(&As[idx]) = v[i];
        }
      }
    }
    {
      const u16x8* src = reinterpret_cast<const u16x8*>(Bt + (size_t)br * K + k0 + bk);
#pragma unroll
      for (int i = 0; i < 4; ++i) {
        u16x8 v = src[i];
        int k = bk + i * 8;
        int idx = (br << 6) + (k ^ ((br & 7) << 3));
        *reinterpret_cast<u16x8*>(&Bs[idx]) = v;
      }
    }
    __syncthreads();
#pragma unroll
    for (int kk = 0; kk < 2; ++kk) {
      short8 af[4], bfr[4];
      const int kb = kk * 32 + (lane >> 4) * 8;
#pragma unroll
      for (int m = 0; m < 4; ++m) {
        int r = wm * 64 + m * 16 + (lane & 15);
        int idx = (r << 6) + (kb ^ ((r & 7) << 3));
        af[m] = *reinterpret_cast<const short8*>(&As[idx]);
      }
#pragma unroll
      for (int n = 0; n < 4; ++n) {
        int c = wn * 64 + n * 16 + (lane & 15);
        int idx = (c << 6) + (kb ^ ((c & 7) << 3));
        bfr[n] = *reinterpret_cast<const short8*>(&Bs[idx]);
      }
#pragma unroll
      for (int m = 0; m < 4; ++m)
#pragma unroll
        for (int n = 0; n < 4; ++n)
          acc[m][n] = __builtin_amdgcn_mfma_f32_16x16x32_bf16(af[m], bfr[n], acc[m][n], 0, 0, 0);
    }
    __syncthreads();
  }

  const int g = lane >> 4;
  const int cl = lane & 15;
  float asv[4], adv[4];
#pragma unroll
  for (int n = 0; n < 4; ++n) {
    int c = wn * 64 + n * 16 + cl;
    asv[n] = a_src[c];
    adv[n] = a_dst[c];
  }
#pragma unroll
  for (int m = 0; m < 4; ++m) {
#pragma unroll
    for (int reg = 0; reg < 4; ++reg) {
      int rl = wm * 64 + m * 16 + g * 4 + reg;
      int row = m0 + rl;
      float ps = 0.f, pd = 0.f;
      if (row < M) {
#pragma unroll
        for (int n = 0; n < 4; ++n) {
          float v = acc[m][n][reg];
          C8[(size_t)row * 256 + wn * 64 + n * 16 + cl] = f2fp8(v);
          ps = fmaf(v, asv[n], ps);
          pd = fmaf(v, adv[n], pd);
        }
      }
#pragma unroll
      for (int off = 1; off < 16; off <<= 1) {
        ps += __shfl_xor(ps, off);
        pd += __shfl_xor(pd, off);
      }
      if (cl == 0) {
        asL[wn * 128 + rl] = ps;
        adL[wn * 128 + rl] = pd;
      }
    }
  }
  __syncthreads();
  if (tid < 128) {
    int row = m0 + tid;
    if (row < M) {
      as_[row] = asL[tid] + asL[128 + tid] + asL[256 + tid] + asL[384 + tid];
      ad_[row] = adL[tid] + adL[128 + tid] + adL[256 + tid] + adL[384 + tid];
    }
  }
}

// ---------------- bucket sort body (inline prefix scan; shared-arena based) ----------------
__device__ __forceinline__ void sort_body(char* smem, int b, const uint* __restrict__ tmp,
                                          const uint* __restrict__ bnxt,
                                          uint* __restrict__ row_ptr, u16* __restrict__ csr) {
  uint* lh = (uint*)smem;                    // 64 u32
  uint* red = (uint*)(smem + 256);           // 8 u32
  uint* buf = (uint*)(smem + 512);           // CAP u32
  int tid = threadIdx.x;
  int lane = tid & 63, wv = tid >> 6;

  // inline exclusive prefix: s0 = sum bnxt[0..b)
  uint part = 0;
  for (int i = tid; i < b; i += 512) part += bnxt[i];
  part = wred_sum_u(part);
  if (lane == 0) red[wv] = part;
  int cnt = (int)bnxt[b];
  if (tid < 64) lh[tid] = 0;
  __syncthreads();
  uint s0 = red[0] + red[1] + red[2] + red[3] + red[4] + red[5] + red[6] + red[7];

  for (int i = tid; i < cnt; i += 512) {
    uint v = tmp[(size_t)b * CAP + i];
    buf[i] = v;
    atomicAdd(&lh[v >> 16], 1u);
  }
  __syncthreads();
  if (tid < 64) {
    uint v = lh[tid];
    uint x = v;
#pragma unroll
    for (int off = 1; off < 64; off <<= 1) {
      uint t = __shfl_up(x, off);
      if (tid >= off) x += t;
    }
    uint pos = s0 + x - v;
    int d = b * 64 + tid;
    if (d < NN) row_ptr[d] = pos;
    lh[tid] = pos;
    if (b == NBUCK - 1 && tid == 0) row_ptr[NN] = s0 + (uint)cnt;
  }
  __syncthreads();
  for (int i = tid; i < cnt; i += 512) {
    uint v = buf[i];
    uint pos = atomicAdd(&lh[v >> 16], 1u);
    csr[pos] = (u16)(v & 0xFFFFu);
  }
}

// ---------------- fused: bucket_sort (blocks < nsort) + GEMM (rest) ----------------
template <bool ABF16>
__global__ __launch_bounds__(512) void gemm_sort(const void* __restrict__ Avoid,
                                                 const u16* __restrict__ Bt,
                                                 u8* __restrict__ C8,
                                                 const float* __restrict__ a_src,
                                                 const float* __restrict__ a_dst,
                                                 float* __restrict__ as_,
                                                 float* __restrict__ ad_,
                                                 int M, int K, int nsort,
                                                 const uint* __restrict__ tmp,
                                                 const uint* __restrict__ bnxt,
                                                 uint* __restrict__ row_ptr,
                                                 u16* __restrict__ csr) {
  __shared__ __align__(16) char smem[53248];
  if ((int)blockIdx.x < nsort) {
    sort_body(smem, blockIdx.x, tmp, bnxt, row_ptr, csr);
  } else {
    gemm_body<ABF16>(smem, blockIdx.x - nsort, Avoid, Bt, C8, a_src, a_dst, as_, ad_, M, K);
  }
}

// decode 16 fp8 from uint4 and fma into acc[16] with weight wg
#define FMA16(v, wg)                                                                   \
  do {                                                                                 \
    f32x2 p_;                                                                          \
    p_ = __builtin_amdgcn_cvt_pk_f32_fp8((v).x, false);                                \
    acc[0] = fmaf((wg), p_.x, acc[0]); acc[1] = fmaf((wg), p_.y, acc[1]);              \
    p_ = __builtin_amdgcn_cvt_pk_f32_fp8((v).x, true);                                 \
    acc[2] = fmaf((wg), p_.x, acc[2]); acc[3] = fmaf((wg), p_.y, acc[3]);              \
    p_ = __builtin_amdgcn_cvt_pk_f32_fp8((v).y, false);                                \
    acc[4] = fmaf((wg), p_.x, acc[4]); acc[5] = fmaf((wg), p_.y, acc[5]);              \
    p_ = __builtin_amdgcn_cvt_pk_f32_fp8((v).y, true);                                 \
    acc[6] = fmaf((wg), p_.x, acc[6]); acc[7] = fmaf((wg), p_.y, acc[7]);              \
    p_ = __builtin_amdgcn_cvt_pk_f32_fp8((v).z, false);                                \
    acc[8] = fmaf((wg), p_.x, acc[8]); acc[9] = fmaf((wg), p_.y, acc[9]);              \
    p_ = __builtin_amdgcn_cvt_pk_f32_fp8((v).z, true);                                 \
    acc[10] = fmaf((wg), p_.x, acc[10]); acc[11] = fmaf((wg), p_.y, acc[11]);          \
    p_ = __builtin_amdgcn_cvt_pk_f32_fp8((v).w, false);                                \
    acc[12] = fmaf((wg), p_.x, acc[12]); acc[13] = fmaf((wg), p_.y, acc[13]);          \
    p_ = __builtin_amdgcn_cvt_pk_f32_fp8((v).w, true);                                 \
    acc[14] = fmaf((wg), p_.x, acc[14]); acc[15] = fmaf((wg), p_.y, acc[15]);          \
  } while (0)

// ---------------- GAT aggregation (fp8 gather, 4 loads in flight); POOL fuses pooling ----------------
template <bool POOL>
__global__ __launch_bounds__(256) void agg_kernel(const uint4* __restrict__ h16,
                                                  const float* __restrict__ as_,
                                                  const float* __restrict__ ad_,
                                                  const uint* __restrict__ row_ptr,
                                                  const u16* __restrict__ csr_src,
                                                  const float* __restrict__ bias,
                                                  u16* __restrict__ out,
                                                  const float* __restrict__ gate_w,
                                                  float* __restrict__ slots, int n) {
  __shared__ float tr[4][4][16][17];
  __shared__ float lp[257];
  int wv = threadIdx.x >> 6;
  int wid = blockIdx.x * 4 + wv;
  int lane = threadIdx.x & 63;
  int g = lane >> 4, li = lane & 15;
  if (POOL) {
    for (int i = threadIdx.x; i < 257; i += 256) lp[i] = 0.f;
    __syncthreads();
  }
  if (wid < n) {
    uint start = row_ptr[wid], end = row_ptr[wid + 1];
    float adi = ad_[wid];
    float acc[16];
#pragma unroll
    for (int c = 0; c < 16; ++c) acc[c] = 0.f;
    float denom = 0.f;
    for (uint base = start; base < end; base += 64) {
      int cnt = (int)(end - base);
      if (cnt > 64) cnt = 64;
      float w = 0.f;
      int s = 0;
      if (lane < cnt) {
        s = (int)csr_src[base + lane];
        float e = as_[s] + adi;
        e = e > 0.f ? e : 0.2f * e;
        w = __expf(e);
      }
      denom += w;
      int j = 0;
      for (; j + 16 <= cnt; j += 16) {
        int s0 = __shfl(s, j + g);
        int s1 = __shfl(s, j + 4 + g);
        int s2 = __shfl(s, j + 8 + g);
        int s3 = __shfl(s, j + 12 + g);
        float w0 = __shfl(w, j + g);
        float w1 = __shfl(w, j + 4 + g);
        float w2 = __shfl(w, j + 8 + g);
        float w3 = __shfl(w, j + 12 + g);
        uint4 v0 = h16[(size_t)s0 * 16 + li];
        uint4 v1 = h16[(size_t)s1 * 16 + li];
        uint4 v2 = h16[(size_t)s2 * 16 + li];
        uint4 v3 = h16[(size_t)s3 * 16 + li];
        FMA16(v0, w0);
        FMA16(v1, w1);
        FMA16(v2, w2);
        FMA16(v3, w3);
      }
      for (; j < cnt; j += 4) {
        int jg = j + g;
        int sg = __shfl(s, jg & 63);
        float wg = __shfl(w, jg & 63);
        if (jg >= cnt) wg = 0.f;
        uint4 v = h16[(size_t)sg * 16 + li];
        FMA16(v, wg);
      }
    }
    denom = wred_sum(denom);
#pragma unroll
    for (int c4 = 0; c4 < 4; ++c4)
      *reinterpret_cast<float4*>(&tr[wv][g][li][c4 * 4]) =
          make_float4(acc[c4 * 4], acc[c4 * 4 + 1], acc[c4 * 4 + 2], acc[c4 * 4 + 3]);
    asm volatile("s_waitcnt lgkmcnt(0)" ::: "memory");
    __builtin_amdgcn_sched_barrier(0);
    float ax = 0.f, ay = 0.f, az = 0.f, aw = 0.f;
#pragma unroll
    for (int gg = 0; gg < 4; ++gg) {
      const float* r = &tr[wv][gg][lane >> 2][4 * (lane & 3)];
      ax += r[0]; ay += r[1]; az += r[2]; aw += r[3];
    }
    float inv = 1.f / (denom + 1e-16f);
    float4 b = reinterpret_cast<const float4*>(bias)[lane];
    float ox = fmaxf(fmaf(ax, inv, b.x), 0.f);
    float oy = fmaxf(fmaf(ay, inv, b.y), 0.f);
    float oz = fmaxf(fmaf(az, inv, b.z), 0.f);
    float ow = fmaxf(fmaf(aw, inv, b.w), 0.f);
    if (!POOL) {
      ushort4 o;
      o.x = f2bf(ox); o.y = f2bf(oy); o.z = f2bf(oz); o.w = f2bf(ow);
      reinterpret_cast<ushort4*>(out)[(size_t)wid * 64 + lane] = o;
    } else {
      float4 gv = reinterpret_cast<const float4*>(gate_w)[lane];
      float pg = wred_sum(ox * gv.x + oy * gv.y + oz * gv.z + ow * gv.w);
      float we = __expf(pg);
      int c0 = lane * 4;
      atomicAdd(&lp[c0 + 0], we * ox);
      atomicAdd(&lp[c0 + 1], we * oy);
      atomicAdd(&lp[c0 + 2], we * oz);
      atomicAdd(&lp[c0 + 3], we * ow);
      if (lane == 0) atomicAdd(&lp[256], we);
    }
  }
  if (POOL) {
    __syncthreads();
    int slot = blockIdx.x & (NSLOT - 1);
    for (int i = threadIdx.x; i < 257; i += 256) {
      float v = lp[i];
      if (v != 0.f) atomicAdd(&slots[slot * SLOTW + i], v);
    }
  }
}

// ---------------- final: reduce slots, normalize ----------------
__global__ void pool3_kernel(const float* __restrict__ slots, float* __restrict__ out) {
  __shared__ float dsh;
  int tid = threadIdx.x;
  float acc = 0.f;
  for (int s = 0; s < NSLOT; ++s) acc += slots[s * SLOTW + tid];
  if (tid == 0) {
    float d = 0.f;
    for (int s = 0; s < NSLOT; ++s) d += slots[s * SLOTW + 256];
    dsh = d;
  }
  __syncthreads();
  out[tid] = acc / dsh;
}

// ---------------- launch ----------------
extern "C" void kernel_launch(void* const* d_in, const int* in_sizes, int n_in,
                              void* d_out, int out_size, void* d_ws, size_t ws_size,
                              hipStream_t stream) {
  const float* x = (const float*)d_in[0];
  const int* edge = (const int*)d_in[1];
  const float* W0 = (const float*)d_in[2];
  const float* a_src0 = (const float*)d_in[3];
  const float* a_dst0 = (const float*)d_in[4];
  const float* b0 = (const float*)d_in[5];
  const float* W1 = (const float*)d_in[6];
  const float* a_src1 = (const float*)d_in[7];
  const float* a_dst1 = (const float*)d_in[8];
  const float* b1 = (const float*)d_in[9];
  const float* gate_w = (const float*)d_in[10];
  float* out = (float*)d_out;

  char* p = (char*)d_ws;
  size_t off = 0;
  auto take = [&](size_t bytes) -> char* {
    char* r = p + off;
    off = (off + bytes + 255) & ~(size_t)255;
    return r;
  };
  u8* hA = (u8*)take((size_t)NN * 256);          // fp8 h (GEMM out, gather operand)
  u16* hB = (u16*)take((size_t)NN * 256 * 2);    // bf16 agg0 out (gemm1 input)
  u16* Wt0 = (u16*)take((size_t)256 * 768 * 2);
  u16* Wt1 = (u16*)take((size_t)256 * 256 * 2);
  float* as0 = (float*)take((size_t)NN * 4);
  float* ad0 = (float*)take((size_t)NN * 4);
  float* as1 = (float*)take((size_t)NN * 4);
  float* ad1 = (float*)take((size_t)NN * 4);
  float* slots = (float*)take((size_t)NSLOT * SLOTW * 4);
  uint* bnxt = (uint*)take((size_t)NBUCK * 4);
  uint* row_ptr = (uint*)take((size_t)(NN + 1) * 4);
  uint* tmp = (uint*)take((size_t)NBUCK * CAP * 4);
  u16* csr = (u16*)take((size_t)ETOT * 2);

  const int* edge_src = edge;
  const int* edge_dst = edge + EE;

  zero_ws<<<1, 1024, 0, stream>>>(bnxt, slots);
  scat_wt<<<NSC + 1024, 256, 0, stream>>>(edge_src, edge_dst, bnxt, tmp, W0, W1, Wt0, Wt1);

  // layer 0 GEMM fused with bucket_sort (independent work, hidden under GEMM)
  gemm_sort<false><<<NBUCK + GEMM_BLOCKS, 512, 0, stream>>>(
      x, Wt0, hA, a_src0, a_dst0, as0, ad0, NN, 768, NBUCK, tmp, bnxt, row_ptr, csr);
  agg_kernel<false><<<12500, 256, 0, stream>>>((const uint4*)hA, as0, ad0, row_ptr, csr, b0, hB,
                                               gate_w, slots, NN);
  gemm_sort<true><<<GEMM_BLOCKS, 512, 0, stream>>>(
      hB, Wt1, hA, a_src1, a_dst1, as1, ad1, NN, 256, 0, tmp, bnxt, row_ptr, csr);
  agg_kernel<true><<<12500, 256, 0, stream>>>((const uint4*)hA, as1, ad1, row_ptr, csr, b1, nullptr,
                                              gate_w, slots, NN);

  pool3_kernel<<<1, 256, 0, stream>>>(slots, out);
}